// Round 14
// baseline (195.307 us; speedup 1.0000x reference)
//
#include <hip/hip_runtime.h>

typedef unsigned short u16;
typedef __bf16 bf16x8 __attribute__((ext_vector_type(8)));
typedef float  f32x16 __attribute__((ext_vector_type(16)));

__device__ __forceinline__ u16 f2bf(float f) {
    union { float f; unsigned u; } v; v.f = f;
    return (u16)((v.u + 0x7fffu + ((v.u >> 16) & 1u)) >> 16);
}

// ---------------------------------------------------------------------------
// 1) s_raw[b][c] = w[b] @ mod_w[c] + mod_b[c]
// ---------------------------------------------------------------------------
__global__ __launch_bounds__(256) void lin_kernel(
    const float* __restrict__ w, const float* __restrict__ mod_w,
    const float* __restrict__ mod_b, float* __restrict__ s_raw)
{
    int gw = (blockIdx.x * 256 + threadIdx.x) >> 6;
    int lane = threadIdx.x & 63;
    int b = gw >> 9, c = gw & 511;
    const float* wr = w + b * 512;
    const float* mr = mod_w + (size_t)c * 512;
    float a = 0.f;
#pragma unroll
    for (int i = 0; i < 8; ++i)
        a = fmaf(wr[lane + i * 64], mr[lane + i * 64], a);
    for (int off = 32; off; off >>= 1) a += __shfl_down(a, off);
    if (!lane) s_raw[gw] = a + mod_b[c];
}

// ---------------------------------------------------------------------------
// 2) s_eff = LeakyReLU(LN(s_raw)) * scale
// ---------------------------------------------------------------------------
__global__ __launch_bounds__(512) void norm_kernel(
    const float* __restrict__ s_raw, const float* __restrict__ ln_g,
    const float* __restrict__ ln_b, const float* __restrict__ scale,
    float* __restrict__ s_eff)
{
    int b = blockIdx.x, c = threadIdx.x;
    __shared__ float rs[512], rq[512];
    float s = s_raw[b * 512 + c];
    rs[c] = s; rq[c] = s * s;
    __syncthreads();
    for (int off = 256; off; off >>= 1) {
        if (c < off) { rs[c] += rs[c + off]; rq[c] += rq[c + off]; }
        __syncthreads();
    }
    float mean = rs[0] * (1.f / 512.f);
    float var  = rq[0] * (1.f / 512.f) - mean * mean;
    float sn = (s - mean) * rsqrtf(var + 1e-5f) * ln_g[c] + ln_b[c];
    sn = sn >= 0.f ? sn : 0.2f * sn;
    s_eff[b * 512 + c] = sn * scale[c];
}

// ---------------------------------------------------------------------------
// 3) wsq[co][ci] = sum_p weight^2 ; wbfT[(p*64+cg)*512*8 + co*8 + cj] = bf16(w)
// ---------------------------------------------------------------------------
__global__ __launch_bounds__(256) void wsq_kernel(
    const float* __restrict__ weight, float* __restrict__ wsq, u16* __restrict__ wbfT)
{
    int idx = blockIdx.x * 256 + threadIdx.x;      // co*512+ci
    int co = idx >> 9, ci = idx & 511;
    int cg = ci >> 3, cj = ci & 7;
    const float* wp = weight + (size_t)idx * 9;
    float s = 0.f;
#pragma unroll
    for (int p = 0; p < 9; ++p) {
        float v = wp[p];
        s += v * v;
        wbfT[((size_t)(p * 64 + cg) * 512 + co) * 8 + cj] = f2bf(v);
    }
    wsq[idx] = s;
}

// ---------------------------------------------------------------------------
// 4) xs[b][h][w][c] (NHWC bf16) = bf16(x[b][c][h][w] * s_eff[b][c])
// ---------------------------------------------------------------------------
__global__ __launch_bounds__(256) void xs_kernel(
    const float* __restrict__ x, const float* __restrict__ s_eff,
    u16* __restrict__ xs)
{
    const int bh = blockIdx.x;
    const int b = bh >> 5, h = bh & 31;
    __shared__ float tile[64][33];
    for (int c0 = 0; c0 < 512; c0 += 64) {
        if (c0) __syncthreads();
        for (int idx = threadIdx.x; idx < 2048; idx += 256) {
            int c = idx >> 5, ww = idx & 31;
            tile[c][ww] = x[(((size_t)b * 512 + c0 + c) * 32 + h) * 32 + ww]
                          * s_eff[b * 512 + c0 + c];
        }
        __syncthreads();
        for (int idx = threadIdx.x; idx < 2048; idx += 256) {
            int ww = idx >> 6, c = idx & 63;
            xs[((b * 32 + h) * 32 + ww) * 512 + c0 + c] = f2bf(tile[c][ww]);
        }
    }
}

// ---------------------------------------------------------------------------
// 5) dsc[b][o] = rsqrt(sum_i s_eff[b][i]^2 * wsq[o][i] + 1e-8)
// ---------------------------------------------------------------------------
__global__ __launch_bounds__(256) void dsc_kernel(
    const float* __restrict__ s_eff, const float* __restrict__ wsq,
    float* __restrict__ dsc)
{
    int gw = (blockIdx.x * 256 + threadIdx.x) >> 6;
    int lane = threadIdx.x & 63;
    int b = gw >> 9, co = gw & 511;
    float a = 0.f;
#pragma unroll
    for (int i = 0; i < 8; ++i) {
        int cin = lane + i * 64;
        float se = s_eff[b * 512 + cin];
        a += se * se * wsq[co * 512 + cin];
    }
    for (int off = 32; off; off >>= 1) a += __shfl_down(a, off);
    if (!lane) dsc[gw] = rsqrtf(a + 1e-8f);
}

// ---------------------------------------------------------------------------
// 6) zero page for halo OOB lanes
// ---------------------------------------------------------------------------
__global__ void zfill_kernel(float* p) { p[threadIdx.x] = 0.f; }

// ---------------------------------------------------------------------------
// 7) conv: A-frags DIRECT global->reg (prefetched one full phase ahead,
//    ~2000 cyc >> L2 latency); LDS holds ONLY B (2 x 16 KB round-dbuf).
//    NO phase barriers (B is round-scoped read-only); ONE lgkm+barrier per
//    round. B staged via reg-split (T14): global->reg at phi0, ds_write at
//    phi2. No explicit vmcnt anywhere -> compiler's counted waits manage
//    A-regs; A-prefetch flies across the round barrier.
//    Grid 256 = 2 mt (XCD-parity) x 128 4-row strips. 512 thr = 8 waves
//    (4 wm x 2 wn), wave 64co x 64px, BM=256, BN=128. Full 48-phase unroll.
//    LDS/CU-phase: 96KB B-reads + ~5KB writes ~ 1200 cyc < MFMA 1536 cyc.
// ---------------------------------------------------------------------------
__global__ __launch_bounds__(512) void conv_kernel(
    const u16* __restrict__ wbfT,  // [576 kflat8][512 co][8]
    const u16* __restrict__ xs,    // [16][32][32][512]
    const float* __restrict__ dsc, // [16][512]
    const u16* __restrict__ zp,    // >=16B zeros
    float* __restrict__ out)       // [16][512][32][32]
{
    __shared__ __align__(16) u16 ldsB[2][8192];    // 2 x 16 KB (13056 used)

    const int tid  = threadIdx.x;
    const int lane = tid & 63;
    const int wv   = tid >> 6;       // 0..7
    const int wm   = wv >> 1;        // 0..3  M-wave (64 co each)
    const int wn   = wv & 1;         // 0..1  N-wave (64 px each)
    const int l31  = lane & 31;
    const int kc8  = lane >> 5;

    const int bx = blockIdx.x;       // 256 blocks
    const int mt = bx & 1;           // XCD-parity-pinned cout half
    const int nt = bx >> 1;          // 0..127
    const int b  = nt >> 3;
    const int h0 = (nt & 7) << 2;    // 4 output rows

    const u16* xsb = xs + (size_t)b * (32 * 32 * 512);

    // ---- A per-lane base: co = mt*256 + wm*64 + l31 (+mf*32), kc8 half ----
    // element off(r,phi,pp,mf,kk) = ((phi*3+pp)*64 + 4r + 2kk)*4096 + mf*256
    const u16* abase = wbfT + ((size_t)(mt * 256 + wm * 64 + l31)) * 8
                            + (size_t)kc8 * 4096;

    // ---- B staging descriptors: 1024 chunks (816 valid); ch = tid+k*512 ----
    // ch = kc*204 + p ; LDS dest byte = ch*16 (matches read layout below)
    const u16* bptr[2]; bool binb[2]; int bdst[2];
#pragma unroll
    for (int k = 0; k < 2; ++k) {
        int ch = tid + k * 512;
        int kc = ch / 204, p = ch % 204;
        int rr = p / 34, cc = p % 34;
        int hh = h0 - 1 + rr, ww = cc - 1;
        binb[k] = (ch < 816) && ((unsigned)hh < 32u) && ((unsigned)ww < 32u);
        bptr[k] = binb[k] ? xsb + (hh * 32 + ww) * 512 + kc * 8 : zp;
        bdst[k] = ch * 16;           // byte offset in buf
    }
    // advance only valid pointers (zp must not drift)
    const int badv[2] = { binb[0] ? 32 : 0, binb[1] ? 32 : 0 };

    f32x16 acc[2][2] = {};
    bf16x8 af[2][3][2][2];           // [parity][pp][mf][kk]
    uint4  bst[2];                   // staged B regs (one round in flight)

    // ---- prologue: B(r0) -> buf0 ; af[0] = A frame t=0 ----
#pragma unroll
    for (int k = 0; k < 2; ++k) {
        bst[k] = *reinterpret_cast<const uint4*>(bptr[k]);
        bptr[k] += badv[k];
        *reinterpret_cast<uint4*>((char*)ldsB[0] + bdst[k]) = bst[k];
    }
#pragma unroll
    for (int pp = 0; pp < 3; ++pp)
#pragma unroll
        for (int mf = 0; mf < 2; ++mf)
#pragma unroll
            for (int kk = 0; kk < 2; ++kk)
                af[0][pp][mf][kk] = *reinterpret_cast<const bf16x8*>(
                    abase + (size_t)(pp * 64 + 2 * kk) * 4096 + mf * 256);
    asm volatile("s_waitcnt lgkmcnt(0)" ::: "memory");
    __builtin_amdgcn_s_barrier();

#pragma unroll
    for (int r = 0; r < 16; ++r) {
#pragma unroll
        for (int phi = 0; phi < 3; ++phi) {
            const int t = r * 3 + phi;
            const char* Bb = (const char*)ldsB[r & 1];

            // ---- prefetch A frame t+1 (full phase of latency cover) ----
            if (t + 1 < 48) {
                const int rn = (t + 1) / 3, pn = (t + 1) % 3;
#pragma unroll
                for (int pp = 0; pp < 3; ++pp)
#pragma unroll
                    for (int mf = 0; mf < 2; ++mf)
#pragma unroll
                        for (int kk = 0; kk < 2; ++kk)
                            af[(t + 1) & 1][pp][mf][kk] =
                                *reinterpret_cast<const bf16x8*>(
                                    abase + (size_t)((pn * 3 + pp) * 64
                                        + 4 * rn + 2 * kk) * 4096 + mf * 256);
            }

            // ---- B stage reg-loads for round r+1 (issued at phi0) ----
            if (phi == 0 && r < 15) {
#pragma unroll
                for (int k = 0; k < 2; ++k) {
                    bst[k] = *reinterpret_cast<const uint4*>(bptr[k]);
                    bptr[k] += badv[k];
                }
            }

            // ---- compute: 12 ds_read + 24 MFMA, compiler-interleaved ----
#pragma unroll
            for (int pp = 0; pp < 3; ++pp)
#pragma unroll
                for (int kk = 0; kk < 2; ++kk) {
                    const int kc = kk * 2 + kc8;
                    const int p0 = (wn * 2 + phi) * 34 + l31 + pp;
                    bf16x8 b0 = *reinterpret_cast<const bf16x8*>(
                        Bb + ((kc * 204 + p0) << 4));
                    bf16x8 b1 = *reinterpret_cast<const bf16x8*>(
                        Bb + ((kc * 204 + p0 + 34) << 4));
                    acc[0][0] = __builtin_amdgcn_mfma_f32_32x32x16_bf16(
                        af[t & 1][pp][0][kk], b0, acc[0][0], 0, 0, 0);
                    acc[0][1] = __builtin_amdgcn_mfma_f32_32x32x16_bf16(
                        af[t & 1][pp][0][kk], b1, acc[0][1], 0, 0, 0);
                    acc[1][0] = __builtin_amdgcn_mfma_f32_32x32x16_bf16(
                        af[t & 1][pp][1][kk], b0, acc[1][0], 0, 0, 0);
                    acc[1][1] = __builtin_amdgcn_mfma_f32_32x32x16_bf16(
                        af[t & 1][pp][1][kk], b1, acc[1][1], 0, 0, 0);
                }

            // ---- round boundary: write staged B, lgkm-drain, barrier ----
            if (phi == 2 && r < 15) {
                char* d = (char*)ldsB[(r + 1) & 1];
#pragma unroll
                for (int k = 0; k < 2; ++k)
                    *reinterpret_cast<uint4*>(d + bdst[k]) = bst[k];
                asm volatile("s_waitcnt lgkmcnt(0)" ::: "memory");
                __builtin_amdgcn_s_barrier();
            }
        }
    }

    // ---- epilogue: C/D col=lane&31, row=(q&3)+8*(q>>2)+4*(lane>>5) ----
    const float* db = dsc + b * 512;
#pragma unroll
    for (int mf = 0; mf < 2; ++mf) {
#pragma unroll
        for (int nf = 0; nf < 2; ++nf) {
            const int h = h0 + wn * 2 + nf, w = l31;
#pragma unroll
            for (int q = 0; q < 16; ++q) {
                int row = (q & 3) + 8 * (q >> 2) + 4 * kc8;
                int co  = mt * 256 + wm * 64 + mf * 32 + row;
                out[(((size_t)b * 512 + co) * 32 + h) * 32 + w]
                    = acc[mf][nf][q] * db[co];
            }
        }
    }
}

// ---------------------------------------------------------------------------
extern "C" void kernel_launch(void* const* d_in, const int* in_sizes, int n_in,
                              void* d_out, int out_size, void* d_ws, size_t ws_size,
                              hipStream_t stream) {
    const float* x      = (const float*)d_in[0];
    const float* w      = (const float*)d_in[1];
    const float* mod_w  = (const float*)d_in[2];
    const float* mod_b  = (const float*)d_in[3];
    const float* ln_g   = (const float*)d_in[4];
    const float* ln_b   = (const float*)d_in[5];
    const float* weight = (const float*)d_in[6];
    const float* scale  = (const float*)d_in[7];
    float* out = (float*)d_out;

    char* ws = (char*)d_ws;
    float* s_raw = (float*)(ws);                     // 32 KB, reused as dsc
    float* dsc   = (float*)(ws);
    float* s_eff = (float*)(ws + 32768);             // 32 KB; head reused as zeros page
    float* wsq   = (float*)(ws + 65536);             // 1 MB
    u16*   wbfT  = (u16*)(ws + 65536 + 1048576);     // 4.5 MB
    u16*   xs    = (u16*)(ws + 65536 + 1048576 + 4718592);  // 16.78 MB
    if (ws_size < 22609920u) return;

    lin_kernel <<<2048, 256, 0, stream>>>(w, mod_w, mod_b, s_raw);
    wsq_kernel <<<1024, 256, 0, stream>>>(weight, wsq, wbfT);
    norm_kernel<<<16, 512, 0, stream>>>(s_raw, ln_g, ln_b, scale, s_eff);
    xs_kernel  <<<512, 256, 0, stream>>>(x, s_eff, xs);
    dsc_kernel <<<2048, 256, 0, stream>>>(s_eff, wsq, dsc);
    zfill_kernel<<<1, 1024, 0, stream>>>(s_eff);     // zeros page (s_eff dead now)
    conv_kernel<<<256, 512, 0, stream>>>(wbfT, xs, dsc, (const u16*)s_eff, out);
}

// Round 15
// 161.481 us; speedup vs baseline: 1.2095x; 1.2095x over previous
//
#include <hip/hip_runtime.h>

typedef unsigned short u16;
typedef __bf16 bf16x8 __attribute__((ext_vector_type(8)));
typedef float  f32x16 __attribute__((ext_vector_type(16)));

__device__ __forceinline__ u16 f2bf(float f) {
    union { float f; unsigned u; } v; v.f = f;
    return (u16)((v.u + 0x7fffu + ((v.u >> 16) & 1u)) >> 16);
}

// ---------------------------------------------------------------------------
// 1) s_raw[b][c] = w[b] @ mod_w[c] + mod_b[c]
// ---------------------------------------------------------------------------
__global__ __launch_bounds__(256) void lin_kernel(
    const float* __restrict__ w, const float* __restrict__ mod_w,
    const float* __restrict__ mod_b, float* __restrict__ s_raw)
{
    int gw = (blockIdx.x * 256 + threadIdx.x) >> 6;
    int lane = threadIdx.x & 63;
    int b = gw >> 9, c = gw & 511;
    const float* wr = w + b * 512;
    const float* mr = mod_w + (size_t)c * 512;
    float a = 0.f;
#pragma unroll
    for (int i = 0; i < 8; ++i)
        a = fmaf(wr[lane + i * 64], mr[lane + i * 64], a);
    for (int off = 32; off; off >>= 1) a += __shfl_down(a, off);
    if (!lane) s_raw[gw] = a + mod_b[c];
}

// ---------------------------------------------------------------------------
// 2) s_eff = LeakyReLU(LN(s_raw)) * scale
// ---------------------------------------------------------------------------
__global__ __launch_bounds__(512) void norm_kernel(
    const float* __restrict__ s_raw, const float* __restrict__ ln_g,
    const float* __restrict__ ln_b, const float* __restrict__ scale,
    float* __restrict__ s_eff)
{
    int b = blockIdx.x, c = threadIdx.x;
    __shared__ float rs[512], rq[512];
    float s = s_raw[b * 512 + c];
    rs[c] = s; rq[c] = s * s;
    __syncthreads();
    for (int off = 256; off; off >>= 1) {
        if (c < off) { rs[c] += rs[c + off]; rq[c] += rq[c + off]; }
        __syncthreads();
    }
    float mean = rs[0] * (1.f / 512.f);
    float var  = rq[0] * (1.f / 512.f) - mean * mean;
    float sn = (s - mean) * rsqrtf(var + 1e-5f) * ln_g[c] + ln_b[c];
    sn = sn >= 0.f ? sn : 0.2f * sn;
    s_eff[b * 512 + c] = sn * scale[c];
}

// ---------------------------------------------------------------------------
// 3) wsq[co][ci] = sum_p weight^2 ; wbfT[(p*64+cg)*512*8 + co*8 + cj] = bf16(w)
// ---------------------------------------------------------------------------
__global__ __launch_bounds__(256) void wsq_kernel(
    const float* __restrict__ weight, float* __restrict__ wsq, u16* __restrict__ wbfT)
{
    int idx = blockIdx.x * 256 + threadIdx.x;      // co*512+ci
    int co = idx >> 9, ci = idx & 511;
    int cg = ci >> 3, cj = ci & 7;
    const float* wp = weight + (size_t)idx * 9;
    float s = 0.f;
#pragma unroll
    for (int p = 0; p < 9; ++p) {
        float v = wp[p];
        s += v * v;
        wbfT[((size_t)(p * 64 + cg) * 512 + co) * 8 + cj] = f2bf(v);
    }
    wsq[idx] = s;
}

// ---------------------------------------------------------------------------
// 4) xs[b][h][w][c] (NHWC bf16) = bf16(x[b][c][h][w] * s_eff[b][c])
// ---------------------------------------------------------------------------
__global__ __launch_bounds__(256) void xs_kernel(
    const float* __restrict__ x, const float* __restrict__ s_eff,
    u16* __restrict__ xs)
{
    const int bh = blockIdx.x;
    const int b = bh >> 5, h = bh & 31;
    __shared__ float tile[64][33];
    for (int c0 = 0; c0 < 512; c0 += 64) {
        if (c0) __syncthreads();
        for (int idx = threadIdx.x; idx < 2048; idx += 256) {
            int c = idx >> 5, ww = idx & 31;
            tile[c][ww] = x[(((size_t)b * 512 + c0 + c) * 32 + h) * 32 + ww]
                          * s_eff[b * 512 + c0 + c];
        }
        __syncthreads();
        for (int idx = threadIdx.x; idx < 2048; idx += 256) {
            int ww = idx >> 6, c = idx & 63;
            xs[((b * 32 + h) * 32 + ww) * 512 + c0 + c] = f2bf(tile[c][ww]);
        }
    }
}

// ---------------------------------------------------------------------------
// 5) dsc[b][o] = rsqrt(sum_i s_eff[b][i]^2 * wsq[o][i] + 1e-8)
// ---------------------------------------------------------------------------
__global__ __launch_bounds__(256) void dsc_kernel(
    const float* __restrict__ s_eff, const float* __restrict__ wsq,
    float* __restrict__ dsc)
{
    int gw = (blockIdx.x * 256 + threadIdx.x) >> 6;
    int lane = threadIdx.x & 63;
    int b = gw >> 9, co = gw & 511;
    float a = 0.f;
#pragma unroll
    for (int i = 0; i < 8; ++i) {
        int cin = lane + i * 64;
        float se = s_eff[b * 512 + cin];
        a += se * se * wsq[co * 512 + cin];
    }
    for (int off = 32; off; off >>= 1) a += __shfl_down(a, off);
    if (!lane) dsc[gw] = rsqrtf(a + 1e-8f);
}

// ---------------------------------------------------------------------------
// 6) zero page for halo OOB lanes
// ---------------------------------------------------------------------------
__global__ void zfill_kernel(float* p) { p[threadIdx.x] = 0.f; }

// ---------------------------------------------------------------------------
// 7) conv: A direct global->reg with THREE NAMED phase buffers (af0/af1/af2 —
//    no runtime indexing, rule #20-proof); B-only LDS (2 x 16 KB round-dbuf);
//    ONE lgkm+barrier per round (B reads and next-round writes hit different
//    buffers, so one barrier suffices). B staged global->reg at phi0,
//    ds_write at phi2 (T14). launch_bounds(512,1) frees the full 256-VGPR
//    budget (R14's spill came from the default occupancy cap + dyn indexing).
//    Grid 256 = 2 mt (XCD-parity) x 128 4-row strips. 512 thr = 8 waves
//    (4 wm x 2 wn), wave 64co x 64px, BM=256, BN=128.
//    LDS/CU-phase: 96 KB B-reads ~ 1130 cyc < MFMA 1536 cyc/SIMD.
// ---------------------------------------------------------------------------
__global__ __launch_bounds__(512, 1) void conv_kernel(
    const u16* __restrict__ wbfT,  // [576 kflat8][512 co][8]
    const u16* __restrict__ xs,    // [16][32][32][512]
    const float* __restrict__ dsc, // [16][512]
    const u16* __restrict__ zp,    // >=16B zeros
    float* __restrict__ out)       // [16][512][32][32]
{
    __shared__ __align__(16) u16 ldsB[2][8192];    // 2 x 16 KB (13056 used)

    const int tid  = threadIdx.x;
    const int lane = tid & 63;
    const int wv   = tid >> 6;       // 0..7
    const int wm   = wv >> 1;        // 0..3  M-wave (64 co each)
    const int wn   = wv & 1;         // 0..1  N-wave (64 px each)
    const int l31  = lane & 31;
    const int kc8  = lane >> 5;

    const int bx = blockIdx.x;       // 256 blocks
    const int mt = bx & 1;           // XCD-parity-pinned cout half
    const int nt = bx >> 1;          // 0..127
    const int b  = nt >> 3;
    const int h0 = (nt & 7) << 2;    // 4 output rows

    const u16* xsb = xs + (size_t)b * (32 * 32 * 512);

    // ---- A per-lane base: co = mt*256 + wm*64 + l31 (+mf*32), kc8 half ----
    const u16* abase = wbfT + ((size_t)(mt * 256 + wm * 64 + l31)) * 8
                            + (size_t)kc8 * 4096;

    // frame(rr, phi) -> 12 frags; element offset:
    //   ((phi*3+pp)*64 + 4*rr + 2*kk)*4096 + mf*256
#define LOADAF(dst, rr, phi)                                                  \
    {                                                                         \
        _Pragma("unroll")                                                     \
        for (int pp = 0; pp < 3; ++pp)                                        \
            _Pragma("unroll")                                                 \
            for (int mf = 0; mf < 2; ++mf)                                    \
                _Pragma("unroll")                                             \
                for (int kk = 0; kk < 2; ++kk)                                \
                    dst[pp][mf][kk] = *reinterpret_cast<const bf16x8*>(       \
                        abase + (size_t)((((phi) * 3 + pp) * 64)              \
                            + 4 * (rr) + 2 * kk) * 4096 + mf * 256);          \
    }

    // ---- B staging descriptors: ch = tid + k*512 (816 valid of 1024) ----
    const u16* bptr[2]; bool binb[2]; int bdst[2];
#pragma unroll
    for (int k = 0; k < 2; ++k) {
        int ch = tid + k * 512;
        int kc = ch / 204, p = ch % 204;
        int rr = p / 34, cc = p % 34;
        int hh = h0 - 1 + rr, ww = cc - 1;
        binb[k] = (ch < 816) && ((unsigned)hh < 32u) && ((unsigned)ww < 32u);
        bptr[k] = binb[k] ? xsb + (hh * 32 + ww) * 512 + kc * 8 : zp;
        bdst[k] = ch * 16;
    }
    const int badv[2] = { binb[0] ? 32 : 0, binb[1] ? 32 : 0 };

    f32x16 acc[2][2] = {};
    bf16x8 af0[3][2][2], af1[3][2][2], af2[3][2][2];
    uint4  bst[2];

    auto compute = [&](bf16x8 (&af)[3][2][2], const char* Bb, int phi) {
#pragma unroll
        for (int pp = 0; pp < 3; ++pp)
#pragma unroll
            for (int kk = 0; kk < 2; ++kk) {
                const int kc = kk * 2 + kc8;
                const int p0 = (wn * 2 + phi) * 34 + l31 + pp;
                bf16x8 b0 = *reinterpret_cast<const bf16x8*>(
                    Bb + ((kc * 204 + p0) << 4));
                bf16x8 b1 = *reinterpret_cast<const bf16x8*>(
                    Bb + ((kc * 204 + p0 + 34) << 4));
                acc[0][0] = __builtin_amdgcn_mfma_f32_32x32x16_bf16(
                    af[pp][0][kk], b0, acc[0][0], 0, 0, 0);
                acc[0][1] = __builtin_amdgcn_mfma_f32_32x32x16_bf16(
                    af[pp][0][kk], b1, acc[0][1], 0, 0, 0);
                acc[1][0] = __builtin_amdgcn_mfma_f32_32x32x16_bf16(
                    af[pp][1][kk], b0, acc[1][0], 0, 0, 0);
                acc[1][1] = __builtin_amdgcn_mfma_f32_32x32x16_bf16(
                    af[pp][1][kk], b1, acc[1][1], 0, 0, 0);
            }
    };

    // ---- prologue: B(r0)->buf0; af0 = frame(0,0) ----
#pragma unroll
    for (int k = 0; k < 2; ++k) {
        bst[k] = *reinterpret_cast<const uint4*>(bptr[k]);
        bptr[k] += badv[k];
        *reinterpret_cast<uint4*>((char*)ldsB[0] + bdst[k]) = bst[k];
    }
    LOADAF(af0, 0, 0);
    asm volatile("s_waitcnt lgkmcnt(0)" ::: "memory");
    __builtin_amdgcn_s_barrier();

    for (int r = 0; r < 16; ++r) {
        const char* Bb = (const char*)ldsB[r & 1];

        // ---- phi 0: prefetch af1, B reg-load for r+1, compute af0 ----
        LOADAF(af1, r, 1);
        if (r < 15) {
#pragma unroll
            for (int k = 0; k < 2; ++k) {
                bst[k] = *reinterpret_cast<const uint4*>(bptr[k]);
                bptr[k] += badv[k];
            }
        }
        compute(af0, Bb, 0);

        // ---- phi 1: prefetch af2, compute af1 ----
        LOADAF(af2, r, 2);
        compute(af1, Bb, 1);

        // ---- phi 2: prefetch af0(r+1), compute af2, commit B, barrier ----
        if (r < 15) {
            LOADAF(af0, r + 1, 0);
            compute(af2, Bb, 2);
            char* d = (char*)ldsB[(r + 1) & 1];
#pragma unroll
            for (int k = 0; k < 2; ++k)
                *reinterpret_cast<uint4*>(d + bdst[k]) = bst[k];
            asm volatile("s_waitcnt lgkmcnt(0)" ::: "memory");
            __builtin_amdgcn_s_barrier();
        } else {
            compute(af2, Bb, 2);
        }
    }

    // ---- epilogue: C/D col=lane&31, row=(q&3)+8*(q>>2)+4*(lane>>5) ----
    const float* db = dsc + b * 512;
#pragma unroll
    for (int mf = 0; mf < 2; ++mf) {
#pragma unroll
        for (int nf = 0; nf < 2; ++nf) {
            const int h = h0 + wn * 2 + nf, w = l31;
#pragma unroll
            for (int q = 0; q < 16; ++q) {
                int row = (q & 3) + 8 * (q >> 2) + 4 * kc8;
                int co  = mt * 256 + wm * 64 + mf * 32 + row;
                out[(((size_t)b * 512 + co) * 32 + h) * 32 + w]
                    = acc[mf][nf][q] * db[co];
            }
        }
    }
#undef LOADAF
}

// ---------------------------------------------------------------------------
extern "C" void kernel_launch(void* const* d_in, const int* in_sizes, int n_in,
                              void* d_out, int out_size, void* d_ws, size_t ws_size,
                              hipStream_t stream) {
    const float* x      = (const float*)d_in[0];
    const float* w      = (const float*)d_in[1];
    const float* mod_w  = (const float*)d_in[2];
    const float* mod_b  = (const float*)d_in[3];
    const float* ln_g   = (const float*)d_in[4];
    const float* ln_b   = (const float*)d_in[5];
    const float* weight = (const float*)d_in[6];
    const float* scale  = (const float*)d_in[7];
    float* out = (float*)d_out;

    char* ws = (char*)d_ws;
    float* s_raw = (float*)(ws);                     // 32 KB, reused as dsc
    float* dsc   = (float*)(ws);
    float* s_eff = (float*)(ws + 32768);             // 32 KB; head reused as zeros page
    float* wsq   = (float*)(ws + 65536);             // 1 MB
    u16*   wbfT  = (u16*)(ws + 65536 + 1048576);     // 4.5 MB
    u16*   xs    = (u16*)(ws + 65536 + 1048576 + 4718592);  // 16.78 MB
    if (ws_size < 22609920u) return;

    lin_kernel <<<2048, 256, 0, stream>>>(w, mod_w, mod_b, s_raw);
    wsq_kernel <<<1024, 256, 0, stream>>>(weight, wsq, wbfT);
    norm_kernel<<<16, 512, 0, stream>>>(s_raw, ln_g, ln_b, scale, s_eff);
    xs_kernel  <<<512, 256, 0, stream>>>(x, s_eff, xs);
    dsc_kernel <<<2048, 256, 0, stream>>>(s_eff, wsq, dsc);
    zfill_kernel<<<1, 1024, 0, stream>>>(s_eff);     // zeros page (s_eff dead now)
    conv_kernel<<<256, 512, 0, stream>>>(wbfT, xs, dsc, (const u16*)s_eff, out);
}

// Round 16
// 161.304 us; speedup vs baseline: 1.2108x; 1.0011x over previous
//
#include <hip/hip_runtime.h>

typedef unsigned short u16;
typedef __bf16 bf16x8 __attribute__((ext_vector_type(8)));
typedef float  f32x16 __attribute__((ext_vector_type(16)));

__device__ __forceinline__ u16 f2bf(float f) {
    union { float f; unsigned u; } v; v.f = f;
    return (u16)((v.u + 0x7fffu + ((v.u >> 16) & 1u)) >> 16);
}

// ---------------------------------------------------------------------------
// 1) s_raw[b][c] = w[b] @ mod_w[c] + mod_b[c]
// ---------------------------------------------------------------------------
__global__ __launch_bounds__(256) void lin_kernel(
    const float* __restrict__ w, const float* __restrict__ mod_w,
    const float* __restrict__ mod_b, float* __restrict__ s_raw)
{
    int gw = (blockIdx.x * 256 + threadIdx.x) >> 6;
    int lane = threadIdx.x & 63;
    int b = gw >> 9, c = gw & 511;
    const float* wr = w + b * 512;
    const float* mr = mod_w + (size_t)c * 512;
    float a = 0.f;
#pragma unroll
    for (int i = 0; i < 8; ++i)
        a = fmaf(wr[lane + i * 64], mr[lane + i * 64], a);
    for (int off = 32; off; off >>= 1) a += __shfl_down(a, off);
    if (!lane) s_raw[gw] = a + mod_b[c];
}

// ---------------------------------------------------------------------------
// 2) s_eff = LeakyReLU(LN(s_raw)) * scale
// ---------------------------------------------------------------------------
__global__ __launch_bounds__(512) void norm_kernel(
    const float* __restrict__ s_raw, const float* __restrict__ ln_g,
    const float* __restrict__ ln_b, const float* __restrict__ scale,
    float* __restrict__ s_eff)
{
    int b = blockIdx.x, c = threadIdx.x;
    __shared__ float rs[512], rq[512];
    float s = s_raw[b * 512 + c];
    rs[c] = s; rq[c] = s * s;
    __syncthreads();
    for (int off = 256; off; off >>= 1) {
        if (c < off) { rs[c] += rs[c + off]; rq[c] += rq[c + off]; }
        __syncthreads();
    }
    float mean = rs[0] * (1.f / 512.f);
    float var  = rq[0] * (1.f / 512.f) - mean * mean;
    float sn = (s - mean) * rsqrtf(var + 1e-5f) * ln_g[c] + ln_b[c];
    sn = sn >= 0.f ? sn : 0.2f * sn;
    s_eff[b * 512 + c] = sn * scale[c];
}

// ---------------------------------------------------------------------------
// 3) wsq[co][ci] = sum_p weight^2 ; wbfT[(p*64+cg)*512*8 + co*8 + cj] = bf16(w)
// ---------------------------------------------------------------------------
__global__ __launch_bounds__(256) void wsq_kernel(
    const float* __restrict__ weight, float* __restrict__ wsq, u16* __restrict__ wbfT)
{
    int idx = blockIdx.x * 256 + threadIdx.x;      // co*512+ci
    int co = idx >> 9, ci = idx & 511;
    int cg = ci >> 3, cj = ci & 7;
    const float* wp = weight + (size_t)idx * 9;
    float s = 0.f;
#pragma unroll
    for (int p = 0; p < 9; ++p) {
        float v = wp[p];
        s += v * v;
        wbfT[((size_t)(p * 64 + cg) * 512 + co) * 8 + cj] = f2bf(v);
    }
    wsq[idx] = s;
}

// ---------------------------------------------------------------------------
// 4) xs[b][h][w][c] (NHWC bf16) = bf16(x[b][c][h][w] * s_eff[b][c])
// ---------------------------------------------------------------------------
__global__ __launch_bounds__(256) void xs_kernel(
    const float* __restrict__ x, const float* __restrict__ s_eff,
    u16* __restrict__ xs)
{
    const int bh = blockIdx.x;
    const int b = bh >> 5, h = bh & 31;
    __shared__ float tile[64][33];
    for (int c0 = 0; c0 < 512; c0 += 64) {
        if (c0) __syncthreads();
        for (int idx = threadIdx.x; idx < 2048; idx += 256) {
            int c = idx >> 5, ww = idx & 31;
            tile[c][ww] = x[(((size_t)b * 512 + c0 + c) * 32 + h) * 32 + ww]
                          * s_eff[b * 512 + c0 + c];
        }
        __syncthreads();
        for (int idx = threadIdx.x; idx < 2048; idx += 256) {
            int ww = idx >> 6, c = idx & 63;
            xs[((b * 32 + h) * 32 + ww) * 512 + c0 + c] = f2bf(tile[c][ww]);
        }
    }
}

// ---------------------------------------------------------------------------
// 5) dsc[b][o] = rsqrt(sum_i s_eff[b][i]^2 * wsq[o][i] + 1e-8)
// ---------------------------------------------------------------------------
__global__ __launch_bounds__(256) void dsc_kernel(
    const float* __restrict__ s_eff, const float* __restrict__ wsq,
    float* __restrict__ dsc)
{
    int gw = (blockIdx.x * 256 + threadIdx.x) >> 6;
    int lane = threadIdx.x & 63;
    int b = gw >> 9, co = gw & 511;
    float a = 0.f;
#pragma unroll
    for (int i = 0; i < 8; ++i) {
        int cin = lane + i * 64;
        float se = s_eff[b * 512 + cin];
        a += se * se * wsq[co * 512 + cin];
    }
    for (int off = 32; off; off >>= 1) a += __shfl_down(a, off);
    if (!lane) dsc[gw] = rsqrtf(a + 1e-8f);
}

// ---------------------------------------------------------------------------
// 6) zero page for halo OOB lanes
// ---------------------------------------------------------------------------
__global__ void zfill_kernel(float* p) { p[threadIdx.x] = 0.f; }

// ---------------------------------------------------------------------------
// 7) conv: A direct global->reg with THREE NAMED phase buffers (af0/af1/af2 —
//    no runtime indexing, rule #20-proof); B-only LDS (2 x 16 KB round-dbuf);
//    ONE lgkm+barrier per round (B reads and next-round writes hit different
//    buffers, so one barrier suffices). B staged global->reg at phi0,
//    ds_write at phi2 (T14). launch_bounds(512,1) frees the full 256-VGPR
//    budget (R14's spill came from the default occupancy cap + dyn indexing).
//    Grid 256 = 2 mt (XCD-parity) x 128 4-row strips. 512 thr = 8 waves
//    (4 wm x 2 wn), wave 64co x 64px, BM=256, BN=128.
//    LDS/CU-phase: 96 KB B-reads ~ 1130 cyc < MFMA 1536 cyc/SIMD.
// ---------------------------------------------------------------------------
__global__ __launch_bounds__(512, 1) void conv_kernel(
    const u16* __restrict__ wbfT,  // [576 kflat8][512 co][8]
    const u16* __restrict__ xs,    // [16][32][32][512]
    const float* __restrict__ dsc, // [16][512]
    const u16* __restrict__ zp,    // >=16B zeros
    float* __restrict__ out)       // [16][512][32][32]
{
    __shared__ __align__(16) u16 ldsB[2][8192];    // 2 x 16 KB (13056 used)

    const int tid  = threadIdx.x;
    const int lane = tid & 63;
    const int wv   = tid >> 6;       // 0..7
    const int wm   = wv >> 1;        // 0..3  M-wave (64 co each)
    const int wn   = wv & 1;         // 0..1  N-wave (64 px each)
    const int l31  = lane & 31;
    const int kc8  = lane >> 5;

    const int bx = blockIdx.x;       // 256 blocks
    const int mt = bx & 1;           // XCD-parity-pinned cout half
    const int nt = bx >> 1;          // 0..127
    const int b  = nt >> 3;
    const int h0 = (nt & 7) << 2;    // 4 output rows

    const u16* xsb = xs + (size_t)b * (32 * 32 * 512);

    // ---- A per-lane base: co = mt*256 + wm*64 + l31 (+mf*32), kc8 half ----
    const u16* abase = wbfT + ((size_t)(mt * 256 + wm * 64 + l31)) * 8
                            + (size_t)kc8 * 4096;

    // frame(rr, phi) -> 12 frags; element offset:
    //   ((phi*3+pp)*64 + 4*rr + 2*kk)*4096 + mf*256
#define LOADAF(dst, rr, phi)                                                  \
    {                                                                         \
        _Pragma("unroll")                                                     \
        for (int pp = 0; pp < 3; ++pp)                                        \
            _Pragma("unroll")                                                 \
            for (int mf = 0; mf < 2; ++mf)                                    \
                _Pragma("unroll")                                             \
                for (int kk = 0; kk < 2; ++kk)                                \
                    dst[pp][mf][kk] = *reinterpret_cast<const bf16x8*>(       \
                        abase + (size_t)((((phi) * 3 + pp) * 64)              \
                            + 4 * (rr) + 2 * kk) * 4096 + mf * 256);          \
    }

    // ---- B staging descriptors: ch = tid + k*512 (816 valid of 1024) ----
    const u16* bptr[2]; bool binb[2]; int bdst[2];
#pragma unroll
    for (int k = 0; k < 2; ++k) {
        int ch = tid + k * 512;
        int kc = ch / 204, p = ch % 204;
        int rr = p / 34, cc = p % 34;
        int hh = h0 - 1 + rr, ww = cc - 1;
        binb[k] = (ch < 816) && ((unsigned)hh < 32u) && ((unsigned)ww < 32u);
        bptr[k] = binb[k] ? xsb + (hh * 32 + ww) * 512 + kc * 8 : zp;
        bdst[k] = ch * 16;
    }
    const int badv[2] = { binb[0] ? 32 : 0, binb[1] ? 32 : 0 };

    f32x16 acc[2][2] = {};
    bf16x8 af0[3][2][2], af1[3][2][2], af2[3][2][2];
    uint4  bst[2];

    auto compute = [&](bf16x8 (&af)[3][2][2], const char* Bb, int phi) {
#pragma unroll
        for (int pp = 0; pp < 3; ++pp)
#pragma unroll
            for (int kk = 0; kk < 2; ++kk) {
                const int kc = kk * 2 + kc8;
                const int p0 = (wn * 2 + phi) * 34 + l31 + pp;
                bf16x8 b0 = *reinterpret_cast<const bf16x8*>(
                    Bb + ((kc * 204 + p0) << 4));
                bf16x8 b1 = *reinterpret_cast<const bf16x8*>(
                    Bb + ((kc * 204 + p0 + 34) << 4));
                acc[0][0] = __builtin_amdgcn_mfma_f32_32x32x16_bf16(
                    af[pp][0][kk], b0, acc[0][0], 0, 0, 0);
                acc[0][1] = __builtin_amdgcn_mfma_f32_32x32x16_bf16(
                    af[pp][0][kk], b1, acc[0][1], 0, 0, 0);
                acc[1][0] = __builtin_amdgcn_mfma_f32_32x32x16_bf16(
                    af[pp][1][kk], b0, acc[1][0], 0, 0, 0);
                acc[1][1] = __builtin_amdgcn_mfma_f32_32x32x16_bf16(
                    af[pp][1][kk], b1, acc[1][1], 0, 0, 0);
            }
    };

    // ---- prologue: B(r0)->buf0; af0 = frame(0,0) ----
#pragma unroll
    for (int k = 0; k < 2; ++k) {
        bst[k] = *reinterpret_cast<const uint4*>(bptr[k]);
        bptr[k] += badv[k];
        *reinterpret_cast<uint4*>((char*)ldsB[0] + bdst[k]) = bst[k];
    }
    LOADAF(af0, 0, 0);
    asm volatile("s_waitcnt lgkmcnt(0)" ::: "memory");
    __builtin_amdgcn_s_barrier();

    for (int r = 0; r < 16; ++r) {
        const char* Bb = (const char*)ldsB[r & 1];

        // ---- phi 0: prefetch af1, B reg-load for r+1, compute af0 ----
        LOADAF(af1, r, 1);
        if (r < 15) {
#pragma unroll
            for (int k = 0; k < 2; ++k) {
                bst[k] = *reinterpret_cast<const uint4*>(bptr[k]);
                bptr[k] += badv[k];
            }
        }
        compute(af0, Bb, 0);

        // ---- phi 1: prefetch af2, compute af1 ----
        LOADAF(af2, r, 2);
        compute(af1, Bb, 1);

        // ---- phi 2: prefetch af0(r+1), compute af2, commit B, barrier ----
        if (r < 15) {
            LOADAF(af0, r + 1, 0);
            compute(af2, Bb, 2);
            char* d = (char*)ldsB[(r + 1) & 1];
#pragma unroll
            for (int k = 0; k < 2; ++k)
                *reinterpret_cast<uint4*>(d + bdst[k]) = bst[k];
            asm volatile("s_waitcnt lgkmcnt(0)" ::: "memory");
            __builtin_amdgcn_s_barrier();
        } else {
            compute(af2, Bb, 2);
        }
    }

    // ---- epilogue: C/D col=lane&31, row=(q&3)+8*(q>>2)+4*(lane>>5) ----
    const float* db = dsc + b * 512;
#pragma unroll
    for (int mf = 0; mf < 2; ++mf) {
#pragma unroll
        for (int nf = 0; nf < 2; ++nf) {
            const int h = h0 + wn * 2 + nf, w = l31;
#pragma unroll
            for (int q = 0; q < 16; ++q) {
                int row = (q & 3) + 8 * (q >> 2) + 4 * kc8;
                int co  = mt * 256 + wm * 64 + mf * 32 + row;
                out[(((size_t)b * 512 + co) * 32 + h) * 32 + w]
                    = acc[mf][nf][q] * db[co];
            }
        }
    }
#undef LOADAF
}

// ---------------------------------------------------------------------------
extern "C" void kernel_launch(void* const* d_in, const int* in_sizes, int n_in,
                              void* d_out, int out_size, void* d_ws, size_t ws_size,
                              hipStream_t stream) {
    const float* x      = (const float*)d_in[0];
    const float* w      = (const float*)d_in[1];
    const float* mod_w  = (const float*)d_in[2];
    const float* mod_b  = (const float*)d_in[3];
    const float* ln_g   = (const float*)d_in[4];
    const float* ln_b   = (const float*)d_in[5];
    const float* weight = (const float*)d_in[6];
    const float* scale  = (const float*)d_in[7];
    float* out = (float*)d_out;

    char* ws = (char*)d_ws;
    float* s_raw = (float*)(ws);                     // 32 KB, reused as dsc
    float* dsc   = (float*)(ws);
    float* s_eff = (float*)(ws + 32768);             // 32 KB; head reused as zeros page
    float* wsq   = (float*)(ws + 65536);             // 1 MB
    u16*   wbfT  = (u16*)(ws + 65536 + 1048576);     // 4.5 MB
    u16*   xs    = (u16*)(ws + 65536 + 1048576 + 4718592);  // 16.78 MB
    if (ws_size < 22609920u) return;

    lin_kernel <<<2048, 256, 0, stream>>>(w, mod_w, mod_b, s_raw);
    wsq_kernel <<<1024, 256, 0, stream>>>(weight, wsq, wbfT);
    norm_kernel<<<16, 512, 0, stream>>>(s_raw, ln_g, ln_b, scale, s_eff);
    xs_kernel  <<<512, 256, 0, stream>>>(x, s_eff, xs);
    dsc_kernel <<<2048, 256, 0, stream>>>(s_eff, wsq, dsc);
    zfill_kernel<<<1, 1024, 0, stream>>>(s_eff);     // zeros page (s_eff dead now)
    conv_kernel<<<256, 512, 0, stream>>>(wbfT, xs, dsc, (const u16*)s_eff, out);
}

// Round 17
// 145.424 us; speedup vs baseline: 1.3430x; 1.1092x over previous
//
#include <hip/hip_runtime.h>

typedef unsigned short u16;
typedef __bf16 bf16x8 __attribute__((ext_vector_type(8)));
typedef float  f32x16 __attribute__((ext_vector_type(16)));

__device__ __forceinline__ u16 f2bf(float f) {
    union { float f; unsigned u; } v; v.f = f;
    return (u16)((v.u + 0x7fffu + ((v.u >> 16) & 1u)) >> 16);
}

// ---------------------------------------------------------------------------
// 1) s_raw[b][c] = w[b] @ mod_w[c] + mod_b[c]
// ---------------------------------------------------------------------------
__global__ __launch_bounds__(256) void lin_kernel(
    const float* __restrict__ w, const float* __restrict__ mod_w,
    const float* __restrict__ mod_b, float* __restrict__ s_raw)
{
    int gw = (blockIdx.x * 256 + threadIdx.x) >> 6;
    int lane = threadIdx.x & 63;
    int b = gw >> 9, c = gw & 511;
    const float* wr = w + b * 512;
    const float* mr = mod_w + (size_t)c * 512;
    float a = 0.f;
#pragma unroll
    for (int i = 0; i < 8; ++i)
        a = fmaf(wr[lane + i * 64], mr[lane + i * 64], a);
    for (int off = 32; off; off >>= 1) a += __shfl_down(a, off);
    if (!lane) s_raw[gw] = a + mod_b[c];
}

// ---------------------------------------------------------------------------
// 2) s_eff = LeakyReLU(LN(s_raw)) * scale
// ---------------------------------------------------------------------------
__global__ __launch_bounds__(512) void norm_kernel(
    const float* __restrict__ s_raw, const float* __restrict__ ln_g,
    const float* __restrict__ ln_b, const float* __restrict__ scale,
    float* __restrict__ s_eff)
{
    int b = blockIdx.x, c = threadIdx.x;
    __shared__ float rs[512], rq[512];
    float s = s_raw[b * 512 + c];
    rs[c] = s; rq[c] = s * s;
    __syncthreads();
    for (int off = 256; off; off >>= 1) {
        if (c < off) { rs[c] += rs[c + off]; rq[c] += rq[c + off]; }
        __syncthreads();
    }
    float mean = rs[0] * (1.f / 512.f);
    float var  = rq[0] * (1.f / 512.f) - mean * mean;
    float sn = (s - mean) * rsqrtf(var + 1e-5f) * ln_g[c] + ln_b[c];
    sn = sn >= 0.f ? sn : 0.2f * sn;
    s_eff[b * 512 + c] = sn * scale[c];
}

// ---------------------------------------------------------------------------
// 3) wsq[co][ci] = sum_p weight^2 ; wbfT[(p*64+cg)*512*8 + co*8 + cj] = bf16(w)
// ---------------------------------------------------------------------------
__global__ __launch_bounds__(256) void wsq_kernel(
    const float* __restrict__ weight, float* __restrict__ wsq, u16* __restrict__ wbfT)
{
    int idx = blockIdx.x * 256 + threadIdx.x;      // co*512+ci
    int co = idx >> 9, ci = idx & 511;
    int cg = ci >> 3, cj = ci & 7;
    const float* wp = weight + (size_t)idx * 9;
    float s = 0.f;
#pragma unroll
    for (int p = 0; p < 9; ++p) {
        float v = wp[p];
        s += v * v;
        wbfT[((size_t)(p * 64 + cg) * 512 + co) * 8 + cj] = f2bf(v);
    }
    wsq[idx] = s;
}

// ---------------------------------------------------------------------------
// 4) xs[b][h][w][c] (NHWC bf16) = bf16(x[b][c][h][w] * s_eff[b][c])
// ---------------------------------------------------------------------------
__global__ __launch_bounds__(256) void xs_kernel(
    const float* __restrict__ x, const float* __restrict__ s_eff,
    u16* __restrict__ xs)
{
    const int bh = blockIdx.x;
    const int b = bh >> 5, h = bh & 31;
    __shared__ float tile[64][33];
    for (int c0 = 0; c0 < 512; c0 += 64) {
        if (c0) __syncthreads();
        for (int idx = threadIdx.x; idx < 2048; idx += 256) {
            int c = idx >> 5, ww = idx & 31;
            tile[c][ww] = x[(((size_t)b * 512 + c0 + c) * 32 + h) * 32 + ww]
                          * s_eff[b * 512 + c0 + c];
        }
        __syncthreads();
        for (int idx = threadIdx.x; idx < 2048; idx += 256) {
            int ww = idx >> 6, c = idx & 63;
            xs[((b * 32 + h) * 32 + ww) * 512 + c0 + c] = f2bf(tile[c][ww]);
        }
    }
}

// ---------------------------------------------------------------------------
// 5) dsc[b][o] = rsqrt(sum_i s_eff[b][i]^2 * wsq[o][i] + 1e-8)
// ---------------------------------------------------------------------------
__global__ __launch_bounds__(256) void dsc_kernel(
    const float* __restrict__ s_eff, const float* __restrict__ wsq,
    float* __restrict__ dsc)
{
    int gw = (blockIdx.x * 256 + threadIdx.x) >> 6;
    int lane = threadIdx.x & 63;
    int b = gw >> 9, co = gw & 511;
    float a = 0.f;
#pragma unroll
    for (int i = 0; i < 8; ++i) {
        int cin = lane + i * 64;
        float se = s_eff[b * 512 + cin];
        a += se * se * wsq[co * 512 + cin];
    }
    for (int off = 32; off; off >>= 1) a += __shfl_down(a, off);
    if (!lane) dsc[gw] = rsqrtf(a + 1e-8f);
}

// ---------------------------------------------------------------------------
// 6) zero page for halo OOB lanes
// ---------------------------------------------------------------------------
__global__ void zfill_kernel(float* p) { p[threadIdx.x] = 0.f; }

// ---------------------------------------------------------------------------
// 7) conv: A direct global->reg, TWO banks of 12 INDIVIDUALLY NAMED frag
//    registers (no arrays, no lambdas -> nothing can be demoted to scratch).
//    B-only LDS (2 x 16 KB round-dbuf); one lgkm+barrier per round (vmcnt
//    never drained -> A prefetch flies across). 6-phase (2-round) explicit
//    body, banks alternate A,B,A,B,A,B. Grid 256 = 2 mt x 128 4-row strips.
//    512 thr = 8 waves (4 wm x 2 wn), wave 64co x 64px, BM=256, BN=128.
//    LDS/CU-phase ~ 96 KB B-reads ~ 1130 cyc < MFMA 1536 cyc/SIMD.
// ---------------------------------------------------------------------------
__global__ __launch_bounds__(512, 1) void conv_kernel(
    const u16* __restrict__ wbfT,  // [576 kflat8][512 co][8]
    const u16* __restrict__ xs,    // [16][32][32][512]
    const float* __restrict__ dsc, // [16][512]
    const u16* __restrict__ zp,    // >=16B zeros
    float* __restrict__ out)       // [16][512][32][32]
{
    __shared__ __align__(16) u16 ldsB[2][8192];    // 2 x 16 KB (13056 used)

    const int tid  = threadIdx.x;
    const int lane = tid & 63;
    const int wv   = tid >> 6;
    const int wm   = wv >> 1;        // 0..3  M-wave (64 co each)
    const int wn   = wv & 1;         // 0..1  N-wave (64 px each)
    const int l31  = lane & 31;
    const int kc8  = lane >> 5;

    const int bx = blockIdx.x;       // 256 blocks
    const int mt = bx & 1;           // XCD-parity-pinned cout half
    const int nt = bx >> 1;          // 0..127
    const int b  = nt >> 3;
    const int h0 = (nt & 7) << 2;    // 4 output rows

    const u16* xsb = xs + (size_t)b * (32 * 32 * 512);

    // A per-lane base: co = mt*256 + wm*64 + l31 (+mf*32), kc8 half
    const u16* abase = wbfT + ((size_t)(mt * 256 + wm * 64 + l31)) * 8
                            + (size_t)kc8 * 4096;

    // B staging descriptors (2 chunks/thread, named scalars)
    const u16 *bptr0, *bptr1; int badv0, badv1, bdst0, bdst1;
    {
        int ch = tid;
        int kc = ch / 204, p = ch % 204;
        int rr = p / 34, cc = p % 34;
        int hh = h0 - 1 + rr, ww = cc - 1;
        bool v = ((unsigned)hh < 32u) && ((unsigned)ww < 32u);
        bptr0 = v ? xsb + (hh * 32 + ww) * 512 + kc * 8 : zp;
        badv0 = v ? 32 : 0;  bdst0 = ch * 16;
        ch = tid + 512;
        kc = ch / 204; p = ch % 204;
        rr = p / 34; cc = p % 34;
        hh = h0 - 1 + rr; ww = cc - 1;
        v = (ch < 816) && ((unsigned)hh < 32u) && ((unsigned)ww < 32u);
        bptr1 = v ? xsb + (hh * 32 + ww) * 512 + kc * 8 : zp;
        badv1 = v ? 32 : 0;  bdst1 = ch * 16;
    }
    char* Bb0 = (char*)ldsB[0];
    char* Bb1 = (char*)ldsB[1];

    f32x16 acc00 = {}, acc01 = {}, acc10 = {}, acc11 = {};
    uint4 bst0, bst1;

    // 24 named A-frag registers: bank fA / fB, _<mf><idx>, idx = pp*2+kk
    bf16x8 fA_00, fA_01, fA_02, fA_03, fA_04, fA_05;
    bf16x8 fA_10, fA_11, fA_12, fA_13, fA_14, fA_15;
    bf16x8 fB_00, fB_01, fB_02, fB_03, fB_04, fB_05;
    bf16x8 fB_10, fB_11, fB_12, fB_13, fB_14, fB_15;

#define AOFF(RR, PHI, PP, KK) \
    ((size_t)((((PHI) * 3 + (PP)) * 64) + 4 * (RR) + 2 * (KK)) * 4096)
#define LDA(OFF) (*reinterpret_cast<const bf16x8*>(abase + (OFF)))
#define LOADA(F, RR, PHI) do {                                          \
    F##_00 = LDA(AOFF(RR, PHI, 0, 0)); F##_10 = LDA(AOFF(RR, PHI, 0, 0) + 256); \
    F##_01 = LDA(AOFF(RR, PHI, 0, 1)); F##_11 = LDA(AOFF(RR, PHI, 0, 1) + 256); \
    F##_02 = LDA(AOFF(RR, PHI, 1, 0)); F##_12 = LDA(AOFF(RR, PHI, 1, 0) + 256); \
    F##_03 = LDA(AOFF(RR, PHI, 1, 1)); F##_13 = LDA(AOFF(RR, PHI, 1, 1) + 256); \
    F##_04 = LDA(AOFF(RR, PHI, 2, 0)); F##_14 = LDA(AOFF(RR, PHI, 2, 0) + 256); \
    F##_05 = LDA(AOFF(RR, PHI, 2, 1)); F##_15 = LDA(AOFF(RR, PHI, 2, 1) + 256); \
} while (0)

#define MFMA4(A0, A1, PP, KK, PHI, BUFP) do {                           \
    const int kc_ = (KK) * 2 + kc8;                                     \
    const int p0_ = (wn * 2 + (PHI)) * 34 + l31 + (PP);                 \
    bf16x8 b0_ = *reinterpret_cast<const bf16x8*>(                      \
        (BUFP) + ((kc_ * 204 + p0_) << 4));                             \
    bf16x8 b1_ = *reinterpret_cast<const bf16x8*>(                      \
        (BUFP) + ((kc_ * 204 + p0_ + 34) << 4));                        \
    acc00 = __builtin_amdgcn_mfma_f32_32x32x16_bf16(A0, b0_, acc00, 0, 0, 0); \
    acc01 = __builtin_amdgcn_mfma_f32_32x32x16_bf16(A0, b1_, acc01, 0, 0, 0); \
    acc10 = __builtin_amdgcn_mfma_f32_32x32x16_bf16(A1, b0_, acc10, 0, 0, 0); \
    acc11 = __builtin_amdgcn_mfma_f32_32x32x16_bf16(A1, b1_, acc11, 0, 0, 0); \
} while (0)

#define COMP(F, PHI, BUFP) do {                                         \
    MFMA4(F##_00, F##_10, 0, 0, PHI, BUFP);                             \
    MFMA4(F##_01, F##_11, 0, 1, PHI, BUFP);                             \
    MFMA4(F##_02, F##_12, 1, 0, PHI, BUFP);                             \
    MFMA4(F##_03, F##_13, 1, 1, PHI, BUFP);                             \
    MFMA4(F##_04, F##_14, 2, 0, PHI, BUFP);                             \
    MFMA4(F##_05, F##_15, 2, 1, PHI, BUFP);                             \
} while (0)

#define BSTLOAD() do {                                                  \
    bst0 = *reinterpret_cast<const uint4*>(bptr0); bptr0 += badv0;      \
    bst1 = *reinterpret_cast<const uint4*>(bptr1); bptr1 += badv1;      \
} while (0)

#define COMMIT(BUFP) do {                                               \
    *reinterpret_cast<uint4*>((BUFP) + bdst0) = bst0;                   \
    *reinterpret_cast<uint4*>((BUFP) + bdst1) = bst1;                   \
    asm volatile("s_waitcnt lgkmcnt(0)" ::: "memory");                  \
    __builtin_amdgcn_s_barrier();                                       \
} while (0)

    // ---- prologue: B(r0)->buf0 (commit+barrier), fA = frame(0,0) ----
    BSTLOAD();
    COMMIT(Bb0);
    LOADA(fA, 0, 0);

    for (int rp = 0; rp < 8; ++rp) {
        const int r0 = 2 * rp, r1 = 2 * rp + 1;
        // (r0,0): bank fA; prefetch fB<-(r0,1); bst load for r0+1
        LOADA(fB, r0, 1);
        BSTLOAD();
        COMP(fA, 0, Bb0);
        // (r0,1): bank fB; prefetch fA<-(r0,2)
        LOADA(fA, r0, 2);
        COMP(fB, 1, Bb0);
        // (r0,2): bank fA; prefetch fB<-(r1,0); commit r1 B -> buf1
        LOADA(fB, r1, 0);
        COMP(fA, 2, Bb0);
        COMMIT(Bb1);
        // (r1,0): bank fB; prefetch fA<-(r1,1); bst load for r1+1
        LOADA(fA, r1, 1);
        if (rp < 7) BSTLOAD();
        COMP(fB, 0, Bb1);
        // (r1,1): bank fA; prefetch fB<-(r1,2)
        LOADA(fB, r1, 2);
        COMP(fA, 1, Bb1);
        // (r1,2): bank fB; prefetch fA<-(r0+2,0); commit next B -> buf0
        if (rp < 7) {
            LOADA(fA, r0 + 2, 0);
            COMP(fB, 2, Bb1);
            COMMIT(Bb0);
        } else {
            COMP(fB, 2, Bb1);
        }
    }

    // ---- epilogue: C/D col=lane&31, row=(q&3)+8*(q>>2)+4*(lane>>5) ----
    const float* db = dsc + b * 512;
#pragma unroll
    for (int mf = 0; mf < 2; ++mf) {
#pragma unroll
        for (int nf = 0; nf < 2; ++nf) {
            const f32x16& a = (mf == 0) ? (nf == 0 ? acc00 : acc01)
                                        : (nf == 0 ? acc10 : acc11);
            const int h = h0 + wn * 2 + nf, w = l31;
#pragma unroll
            for (int q = 0; q < 16; ++q) {
                int row = (q & 3) + 8 * (q >> 2) + 4 * kc8;
                int co  = mt * 256 + wm * 64 + mf * 32 + row;
                out[(((size_t)b * 512 + co) * 32 + h) * 32 + w]
                    = a[q] * db[co];
            }
        }
    }
#undef AOFF
#undef LDA
#undef LOADA
#undef MFMA4
#undef COMP
#undef BSTLOAD
#undef COMMIT
}

// ---------------------------------------------------------------------------
extern "C" void kernel_launch(void* const* d_in, const int* in_sizes, int n_in,
                              void* d_out, int out_size, void* d_ws, size_t ws_size,
                              hipStream_t stream) {
    const float* x      = (const float*)d_in[0];
    const float* w      = (const float*)d_in[1];
    const float* mod_w  = (const float*)d_in[2];
    const float* mod_b  = (const float*)d_in[3];
    const float* ln_g   = (const float*)d_in[4];
    const float* ln_b   = (const float*)d_in[5];
    const float* weight = (const float*)d_in[6];
    const float* scale  = (const float*)d_in[7];
    float* out = (float*)d_out;

    char* ws = (char*)d_ws;
    float* s_raw = (float*)(ws);                     // 32 KB, reused as dsc
    float* dsc   = (float*)(ws);
    float* s_eff = (float*)(ws + 32768);             // 32 KB; head reused as zeros page
    float* wsq   = (float*)(ws + 65536);             // 1 MB
    u16*   wbfT  = (u16*)(ws + 65536 + 1048576);     // 4.5 MB
    u16*   xs    = (u16*)(ws + 65536 + 1048576 + 4718592);  // 16.78 MB
    if (ws_size < 22609920u) return;

    lin_kernel <<<2048, 256, 0, stream>>>(w, mod_w, mod_b, s_raw);
    wsq_kernel <<<1024, 256, 0, stream>>>(weight, wsq, wbfT);
    norm_kernel<<<16, 512, 0, stream>>>(s_raw, ln_g, ln_b, scale, s_eff);
    xs_kernel  <<<512, 256, 0, stream>>>(x, s_eff, xs);
    dsc_kernel <<<2048, 256, 0, stream>>>(s_eff, wsq, dsc);
    zfill_kernel<<<1, 1024, 0, stream>>>(s_eff);     // zeros page (s_eff dead now)
    conv_kernel<<<256, 512, 0, stream>>>(wbfT, xs, dsc, (const u16*)s_eff, out);
}

// Round 18
// 127.829 us; speedup vs baseline: 1.5279x; 1.1376x over previous
//
#include <hip/hip_runtime.h>

typedef unsigned short u16;
typedef __bf16 bf16x8 __attribute__((ext_vector_type(8)));
typedef float  f32x16 __attribute__((ext_vector_type(16)));

__device__ __forceinline__ u16 f2bf(float f) {
    union { float f; unsigned u; } v; v.f = f;
    return (u16)((v.u + 0x7fffu + ((v.u >> 16) & 1u)) >> 16);
}

#define GLD16(gsrc, ldst) \
    __builtin_amdgcn_global_load_lds( \
        (const __attribute__((address_space(1))) void*)(gsrc), \
        (__attribute__((address_space(3))) void*)(ldst), 16, 0, 0)

// ---------------------------------------------------------------------------
// 1) s_raw[b][c] = w[b] @ mod_w[c] + mod_b[c]
// ---------------------------------------------------------------------------
__global__ __launch_bounds__(256) void lin_kernel(
    const float* __restrict__ w, const float* __restrict__ mod_w,
    const float* __restrict__ mod_b, float* __restrict__ s_raw)
{
    int gw = (blockIdx.x * 256 + threadIdx.x) >> 6;
    int lane = threadIdx.x & 63;
    int b = gw >> 9, c = gw & 511;
    const float* wr = w + b * 512;
    const float* mr = mod_w + (size_t)c * 512;
    float a = 0.f;
#pragma unroll
    for (int i = 0; i < 8; ++i)
        a = fmaf(wr[lane + i * 64], mr[lane + i * 64], a);
    for (int off = 32; off; off >>= 1) a += __shfl_down(a, off);
    if (!lane) s_raw[gw] = a + mod_b[c];
}

// ---------------------------------------------------------------------------
// 2) s_eff = LeakyReLU(LN(s_raw)) * scale
// ---------------------------------------------------------------------------
__global__ __launch_bounds__(512) void norm_kernel(
    const float* __restrict__ s_raw, const float* __restrict__ ln_g,
    const float* __restrict__ ln_b, const float* __restrict__ scale,
    float* __restrict__ s_eff)
{
    int b = blockIdx.x, c = threadIdx.x;
    __shared__ float rs[512], rq[512];
    float s = s_raw[b * 512 + c];
    rs[c] = s; rq[c] = s * s;
    __syncthreads();
    for (int off = 256; off; off >>= 1) {
        if (c < off) { rs[c] += rs[c + off]; rq[c] += rq[c + off]; }
        __syncthreads();
    }
    float mean = rs[0] * (1.f / 512.f);
    float var  = rq[0] * (1.f / 512.f) - mean * mean;
    float sn = (s - mean) * rsqrtf(var + 1e-5f) * ln_g[c] + ln_b[c];
    sn = sn >= 0.f ? sn : 0.2f * sn;
    s_eff[b * 512 + c] = sn * scale[c];
}

// ---------------------------------------------------------------------------
// 3) wsq[co][ci] = sum_p weight^2 ; wbfT[(p*64+cg)*512*8 + co*8 + cj] = bf16(w)
// ---------------------------------------------------------------------------
__global__ __launch_bounds__(256) void wsq_kernel(
    const float* __restrict__ weight, float* __restrict__ wsq, u16* __restrict__ wbfT)
{
    int idx = blockIdx.x * 256 + threadIdx.x;      // co*512+ci
    int co = idx >> 9, ci = idx & 511;
    int cg = ci >> 3, cj = ci & 7;
    const float* wp = weight + (size_t)idx * 9;
    float s = 0.f;
#pragma unroll
    for (int p = 0; p < 9; ++p) {
        float v = wp[p];
        s += v * v;
        wbfT[((size_t)(p * 64 + cg) * 512 + co) * 8 + cj] = f2bf(v);
    }
    wsq[idx] = s;
}

// ---------------------------------------------------------------------------
// 4) xs[b][h][w][c] (NHWC bf16) = bf16(x[b][c][h][w] * s_eff[b][c])
// ---------------------------------------------------------------------------
__global__ __launch_bounds__(256) void xs_kernel(
    const float* __restrict__ x, const float* __restrict__ s_eff,
    u16* __restrict__ xs)
{
    const int bh = blockIdx.x;
    const int b = bh >> 5, h = bh & 31;
    __shared__ float tile[64][33];
    for (int c0 = 0; c0 < 512; c0 += 64) {
        if (c0) __syncthreads();
        for (int idx = threadIdx.x; idx < 2048; idx += 256) {
            int c = idx >> 5, ww = idx & 31;
            tile[c][ww] = x[(((size_t)b * 512 + c0 + c) * 32 + h) * 32 + ww]
                          * s_eff[b * 512 + c0 + c];
        }
        __syncthreads();
        for (int idx = threadIdx.x; idx < 2048; idx += 256) {
            int ww = idx >> 6, c = idx & 63;
            xs[((b * 32 + h) * 32 + ww) * 512 + c0 + c] = f2bf(tile[c][ww]);
        }
    }
}

// ---------------------------------------------------------------------------
// 5) dsc[b][o] = rsqrt(sum_i s_eff[b][i]^2 * wsq[o][i] + 1e-8)
// ---------------------------------------------------------------------------
__global__ __launch_bounds__(256) void dsc_kernel(
    const float* __restrict__ s_eff, const float* __restrict__ wsq,
    float* __restrict__ dsc)
{
    int gw = (blockIdx.x * 256 + threadIdx.x) >> 6;
    int lane = threadIdx.x & 63;
    int b = gw >> 9, co = gw & 511;
    float a = 0.f;
#pragma unroll
    for (int i = 0; i < 8; ++i) {
        int cin = lane + i * 64;
        float se = s_eff[b * 512 + cin];
        a += se * se * wsq[co * 512 + cin];
    }
    for (int off = 32; off; off >>= 1) a += __shfl_down(a, off);
    if (!lane) dsc[gw] = rsqrtf(a + 1e-8f);
}

// ---------------------------------------------------------------------------
// 6) zero page for halo OOB lanes
// ---------------------------------------------------------------------------
__global__ void zfill_kernel(float* p) { p[threadIdx.x] = 0.f; }

// ---------------------------------------------------------------------------
// 7) conv, R11 machine with 4 waves of 128x64 (frag-read traffic -25%).
//    Grid 256 = 2 mt (XCD-parity) x 128 4-row strips. 256 thr = 4 waves
//    (2 wm x 2 wn), wave 128co x 64px, BM=256, BN=128, 32x32x16 MFMA.
//    A: [2 buf][3 pp][4 kc][256 co][16B] 48KB/buf, gld_lds staged one phase
//       ahead (12/thread, single base ptr + compile-time offsets since
//       co == tid at 256 thr).  B: [2 buf][4 kc][204 p][16B] 16KB/buf,
//       staged one round ahead at phi=1 (4/thread).
//    kc-major => consecutive-16B frag reads, 0 bank conflicts (R11-proven).
//    Phase: {stage issues | per-pp (12 ds_read -> 16 MFMA) x3 | vmcnt0 | bar}.
// ---------------------------------------------------------------------------
__global__ __launch_bounds__(256, 1) void conv_kernel(
    const u16* __restrict__ wbfT,  // [576 kflat8][512 co][8]
    const u16* __restrict__ xs,    // [16][32][32][512]
    const float* __restrict__ dsc, // [16][512]
    const u16* __restrict__ zp,    // >=16B zeros
    float* __restrict__ out)       // [16][512][32][32]
{
    __shared__ __align__(16) u16 ldsA[2][24576];   // 2 x 48 KB
    __shared__ __align__(16) u16 ldsB[2][8192];    // 2 x 16 KB (13056 used)

    const int tid  = threadIdx.x;
    const int lane = tid & 63;
    const int wv   = tid >> 6;       // 0..3
    const int wm   = wv >> 1;        // 0..1  M-wave (128 co each)
    const int wn   = wv & 1;         // 0..1  N-wave (64 px each)
    const int l31  = lane & 31;
    const int kc8  = lane >> 5;

    const int bx = blockIdx.x;       // 256 blocks
    const int mt = bx & 1;           // XCD-parity-pinned cout half
    const int nt = bx >> 1;          // 0..127
    const int b  = nt >> 3;
    const int h0 = (nt & 7) << 2;    // 4 output rows

    const u16* xsb = xs + (size_t)b * (32 * 32 * 512);

    // ---- A staging: 3072 chunks, 12/thread; chunk k: (pp=k>>2, kc=k&3,
    //      co=tid).  Source = A0 + ((k>>2)*64 + (k&3))*4096 (compile-time),
    //      A0 advanced per phase.  LDS dest = wv*1024 + k*4096 (linear). ----
    const u16* A0 = wbfT + ((size_t)(mt * 256 + tid)) * 8;
    char* adst = (char*)nullptr;     // set per stage

    // ---- B staging: 816 chunks, 4/thread (k=3 only tid<48) ----
    const u16* bsrc[4];
#pragma unroll
    for (int k = 0; k < 4; ++k) {
        int ch = tid + k * 256;
        int kc = ch / 204, p = ch % 204;
        int rr = p / 34, cc = p % 34;
        int hh = h0 - 1 + rr, ww = cc - 1;
        bool inb = (ch < 816) && ((unsigned)hh < 32u) && ((unsigned)ww < 32u);
        bsrc[k] = inb ? xsb + (hh * 32 + ww) * 512 + kc * 8 : zp;
    }

    f32x16 acc[4][2] = {};           // [mf][nf]

    // ---- prologue: A(t=0)->buf0, B(r0)->buf0; full drain ----
    {
        char* d = (char*)ldsA[0] + wv * 1024;
#pragma unroll
        for (int k = 0; k < 12; ++k)
            GLD16(A0 + (size_t)((k >> 2) * 64 + (k & 3)) * 4096, d + k * 4096);
        A0 += (size_t)192 * 4096;    // -> (r0, phi1)
        char* db = (char*)ldsB[0] + wv * 1024;
#pragma unroll
        for (int k = 0; k < 3; ++k) GLD16(bsrc[k], db + k * 4096);
        if (tid < 48) GLD16(bsrc[3], db + 3 * 4096);
    }
    asm volatile("s_waitcnt vmcnt(0)" ::: "memory");
    __builtin_amdgcn_s_barrier();

    int pidx = 0;
    for (int r = 0; r < 16; ++r) {
        const char* Bb = (const char*)ldsB[r & 1];
        const bool lastR = (r == 15);

#pragma unroll
        for (int phi = 0; phi < 3; ++phi) {
            const int abuf = pidx & 1;
            const char* Ab = (const char*)ldsA[abuf];
            const bool lastPhase = lastR && (phi == 2);

            // ---- stage issues (whole phase to land) ----
            if (!lastPhase) {
                char* d = (char*)ldsA[abuf ^ 1] + wv * 1024;
#pragma unroll
                for (int k = 0; k < 12; ++k)
                    GLD16(A0 + (size_t)((k >> 2) * 64 + (k & 3)) * 4096,
                          d + k * 4096);
                A0 += (size_t)(phi == 1 ? -380 : 192) * 4096;
            }
            if (phi == 1 && !lastR) {
#pragma unroll
                for (int k = 0; k < 4; ++k) bsrc[k] += 32;   // next cin grp
                char* db = (char*)ldsB[(r + 1) & 1] + wv * 1024;
#pragma unroll
                for (int k = 0; k < 3; ++k) GLD16(bsrc[k], db + k * 4096);
                if (tid < 48) GLD16(bsrc[3], db + 3 * 4096);
            }

            // ---- 3x {12 ds_read -> 16 MFMA}, compiler-interleaved ----
#pragma unroll
            for (int pp = 0; pp < 3; ++pp) {
                bf16x8 af[4][2], bfr[2][2];
#pragma unroll
                for (int kk = 0; kk < 2; ++kk) {
                    const int kc = kk * 2 + kc8;
#pragma unroll
                    for (int mf = 0; mf < 4; ++mf) {
                        const int cl = wm * 128 + mf * 32 + l31;
                        af[mf][kk] = *reinterpret_cast<const bf16x8*>(
                            Ab + (pp * 4 + kc) * 4096 + cl * 16);
                    }
#pragma unroll
                    for (int nf = 0; nf < 2; ++nf) {
                        const int p = (wn * 2 + nf + phi) * 34 + l31 + pp;
                        bfr[nf][kk] = *reinterpret_cast<const bf16x8*>(
                            Bb + ((kc * 204 + p) << 4));
                    }
                }
#pragma unroll
                for (int kk = 0; kk < 2; ++kk)
#pragma unroll
                    for (int mf = 0; mf < 4; ++mf) {
                        acc[mf][0] = __builtin_amdgcn_mfma_f32_32x32x16_bf16(
                            af[mf][kk], bfr[0][kk], acc[mf][0], 0, 0, 0);
                        acc[mf][1] = __builtin_amdgcn_mfma_f32_32x32x16_bf16(
                            af[mf][kk], bfr[1][kk], acc[mf][1], 0, 0, 0);
                    }
            }

            // ---- phase tail: staged loads drained, buffers swap safe ----
            if (!lastPhase) {
                asm volatile("s_waitcnt vmcnt(0)" ::: "memory");
                __builtin_amdgcn_s_barrier();
            }
            ++pidx;
        }
    }

    // ---- epilogue: C/D col=lane&31, row=(q&3)+8*(q>>2)+4*(lane>>5) ----
    const float* db = dsc + b * 512;
#pragma unroll
    for (int mf = 0; mf < 4; ++mf) {
#pragma unroll
        for (int nf = 0; nf < 2; ++nf) {
            const int h = h0 + wn * 2 + nf, w = l31;
#pragma unroll
            for (int q = 0; q < 16; ++q) {
                int row = (q & 3) + 8 * (q >> 2) + 4 * kc8;
                int co  = mt * 256 + wm * 128 + mf * 32 + row;
                out[(((size_t)b * 512 + co) * 32 + h) * 32 + w]
                    = acc[mf][nf][q] * db[co];
            }
        }
    }
}

// ---------------------------------------------------------------------------
extern "C" void kernel_launch(void* const* d_in, const int* in_sizes, int n_in,
                              void* d_out, int out_size, void* d_ws, size_t ws_size,
                              hipStream_t stream) {
    const float* x      = (const float*)d_in[0];
    const float* w      = (const float*)d_in[1];
    const float* mod_w  = (const float*)d_in[2];
    const float* mod_b  = (const float*)d_in[3];
    const float* ln_g   = (const float*)d_in[4];
    const float* ln_b   = (const float*)d_in[5];
    const float* weight = (const float*)d_in[6];
    const float* scale  = (const float*)d_in[7];
    float* out = (float*)d_out;

    char* ws = (char*)d_ws;
    float* s_raw = (float*)(ws);                     // 32 KB, reused as dsc
    float* dsc   = (float*)(ws);
    float* s_eff = (float*)(ws + 32768);             // 32 KB; head reused as zeros page
    float* wsq   = (float*)(ws + 65536);             // 1 MB
    u16*   wbfT  = (u16*)(ws + 65536 + 1048576);     // 4.5 MB
    u16*   xs    = (u16*)(ws + 65536 + 1048576 + 4718592);  // 16.78 MB
    if (ws_size < 22609920u) return;

    lin_kernel <<<2048, 256, 0, stream>>>(w, mod_w, mod_b, s_raw);
    wsq_kernel <<<1024, 256, 0, stream>>>(weight, wsq, wbfT);
    norm_kernel<<<16, 512, 0, stream>>>(s_raw, ln_g, ln_b, scale, s_eff);
    xs_kernel  <<<512, 256, 0, stream>>>(x, s_eff, xs);
    dsc_kernel <<<2048, 256, 0, stream>>>(s_eff, wsq, dsc);
    zfill_kernel<<<1, 1024, 0, stream>>>(s_eff);     // zeros page (s_eff dead now)
    conv_kernel<<<256, 256, 0, stream>>>(wbfT, xs, dsc, (const u16*)s_eff, out);
}

// Round 19
// 119.554 us; speedup vs baseline: 1.6336x; 1.0692x over previous
//
#include <hip/hip_runtime.h>

typedef unsigned short u16;
typedef __bf16 bf16x8 __attribute__((ext_vector_type(8)));
typedef float  f32x16 __attribute__((ext_vector_type(16)));

__device__ __forceinline__ u16 f2bf(float f) {
    union { float f; unsigned u; } v; v.f = f;
    return (u16)((v.u + 0x7fffu + ((v.u >> 16) & 1u)) >> 16);
}

#define GLD16(gsrc, ldst) \
    __builtin_amdgcn_global_load_lds( \
        (const __attribute__((address_space(1))) void*)(gsrc), \
        (__attribute__((address_space(3))) void*)(ldst), 16, 0, 0)

// ---------------------------------------------------------------------------
// 1) s_raw[b][c] = w[b] @ mod_w[c] + mod_b[c]
// ---------------------------------------------------------------------------
__global__ __launch_bounds__(256) void lin_kernel(
    const float* __restrict__ w, const float* __restrict__ mod_w,
    const float* __restrict__ mod_b, float* __restrict__ s_raw)
{
    int gw = (blockIdx.x * 256 + threadIdx.x) >> 6;
    int lane = threadIdx.x & 63;
    int b = gw >> 9, c = gw & 511;
    const float* wr = w + b * 512;
    const float* mr = mod_w + (size_t)c * 512;
    float a = 0.f;
#pragma unroll
    for (int i = 0; i < 8; ++i)
        a = fmaf(wr[lane + i * 64], mr[lane + i * 64], a);
    for (int off = 32; off; off >>= 1) a += __shfl_down(a, off);
    if (!lane) s_raw[gw] = a + mod_b[c];
}

// ---------------------------------------------------------------------------
// 2) s_eff = LeakyReLU(LN(s_raw)) * scale
// ---------------------------------------------------------------------------
__global__ __launch_bounds__(512) void norm_kernel(
    const float* __restrict__ s_raw, const float* __restrict__ ln_g,
    const float* __restrict__ ln_b, const float* __restrict__ scale,
    float* __restrict__ s_eff)
{
    int b = blockIdx.x, c = threadIdx.x;
    __shared__ float rs[512], rq[512];
    float s = s_raw[b * 512 + c];
    rs[c] = s; rq[c] = s * s;
    __syncthreads();
    for (int off = 256; off; off >>= 1) {
        if (c < off) { rs[c] += rs[c + off]; rq[c] += rq[c + off]; }
        __syncthreads();
    }
    float mean = rs[0] * (1.f / 512.f);
    float var  = rq[0] * (1.f / 512.f) - mean * mean;
    float sn = (s - mean) * rsqrtf(var + 1e-5f) * ln_g[c] + ln_b[c];
    sn = sn >= 0.f ? sn : 0.2f * sn;
    s_eff[b * 512 + c] = sn * scale[c];
}

// ---------------------------------------------------------------------------
// 3) wsq[co][ci] = sum_p weight^2 ; wbfT[(p*64+cg)*512*8 + co*8 + cj] = bf16(w)
// ---------------------------------------------------------------------------
__global__ __launch_bounds__(256) void wsq_kernel(
    const float* __restrict__ weight, float* __restrict__ wsq, u16* __restrict__ wbfT)
{
    int idx = blockIdx.x * 256 + threadIdx.x;      // co*512+ci
    int co = idx >> 9, ci = idx & 511;
    int cg = ci >> 3, cj = ci & 7;
    const float* wp = weight + (size_t)idx * 9;
    float s = 0.f;
#pragma unroll
    for (int p = 0; p < 9; ++p) {
        float v = wp[p];
        s += v * v;
        wbfT[((size_t)(p * 64 + cg) * 512 + co) * 8 + cj] = f2bf(v);
    }
    wsq[idx] = s;
}

// ---------------------------------------------------------------------------
// 4) xs[b][h][w][c] (NHWC bf16) = bf16(x[b][c][h][w] * s_eff[b][c])
// ---------------------------------------------------------------------------
__global__ __launch_bounds__(256) void xs_kernel(
    const float* __restrict__ x, const float* __restrict__ s_eff,
    u16* __restrict__ xs)
{
    const int bh = blockIdx.x;
    const int b = bh >> 5, h = bh & 31;
    __shared__ float tile[64][33];
    for (int c0 = 0; c0 < 512; c0 += 64) {
        if (c0) __syncthreads();
        for (int idx = threadIdx.x; idx < 2048; idx += 256) {
            int c = idx >> 5, ww = idx & 31;
            tile[c][ww] = x[(((size_t)b * 512 + c0 + c) * 32 + h) * 32 + ww]
                          * s_eff[b * 512 + c0 + c];
        }
        __syncthreads();
        for (int idx = threadIdx.x; idx < 2048; idx += 256) {
            int ww = idx >> 6, c = idx & 63;
            xs[((b * 32 + h) * 32 + ww) * 512 + c0 + c] = f2bf(tile[c][ww]);
        }
    }
}

// ---------------------------------------------------------------------------
// 5) dsc[b][o] = rsqrt(sum_i s_eff[b][i]^2 * wsq[o][i] + 1e-8)
// ---------------------------------------------------------------------------
__global__ __launch_bounds__(256) void dsc_kernel(
    const float* __restrict__ s_eff, const float* __restrict__ wsq,
    float* __restrict__ dsc)
{
    int gw = (blockIdx.x * 256 + threadIdx.x) >> 6;
    int lane = threadIdx.x & 63;
    int b = gw >> 9, co = gw & 511;
    float a = 0.f;
#pragma unroll
    for (int i = 0; i < 8; ++i) {
        int cin = lane + i * 64;
        float se = s_eff[b * 512 + cin];
        a += se * se * wsq[co * 512 + cin];
    }
    for (int off = 32; off; off >>= 1) a += __shfl_down(a, off);
    if (!lane) dsc[gw] = rsqrtf(a + 1e-8f);
}

// ---------------------------------------------------------------------------
// 6) zero page for halo OOB lanes
// ---------------------------------------------------------------------------
__global__ void zfill_kernel(float* p) { p[threadIdx.x] = 0.f; }

// ---------------------------------------------------------------------------
// 7) conv, R11 phase machine + K-SPLIT waves: 8 waves = 2wm x 2wn x 2ks,
//    wave tile 128co x 64px x half-K (ks picks kc pair; kc8 lane split is
//    intrinsic to the 32x32x16 operand layout). Frag reads/phase: 144 vs
//    R11's 192 (-25%) at the SAME 8 waves/CU and same MFMA total.
//    Sync/staging/layout byte-identical to R11 (87.8us): A [2buf][3pp][4kc]
//    [256co][16B] staged one phase ahead, B [2buf][4kc][204p][16B] staged
//    at phi=1, per-phase vmcnt(0)+barrier, lgkm fences, setprio.
//    Epilogue: ks=1 waves dump acc into dead ldsA/ldsB (128KB exact),
//    ks=0 waves add partials and store.
// ---------------------------------------------------------------------------
__global__ __launch_bounds__(512, 1) void conv_kernel(
    const u16* __restrict__ wbfT,  // [576 kflat8][512 co][8]
    const u16* __restrict__ xs,    // [16][32][32][512]
    const float* __restrict__ dsc, // [16][512]
    const u16* __restrict__ zp,    // >=16B zeros
    float* __restrict__ out)       // [16][512][32][32]
{
    __shared__ __align__(16) u16 ldsA[2][24576];   // 2 x 48 KB
    __shared__ __align__(16) u16 ldsB[2][8192];    // 2 x 16 KB (13056 used)

    const int tid  = threadIdx.x;
    const int lane = tid & 63;
    const int wv   = tid >> 6;       // 0..7
    const int wm   = wv >> 2;        // 0..1  M-wave (128 co each)
    const int wn   = (wv >> 1) & 1;  // 0..1  N-wave (64 px each)
    const int ks   = wv & 1;         // 0..1  K-split (kc pair)
    const int l31  = lane & 31;
    const int kc8  = lane >> 5;

    const int bx = blockIdx.x;       // 256 blocks
    const int mt = bx & 1;           // XCD-parity-pinned cout half
    const int nt = bx >> 1;          // 0..127
    const int b  = nt >> 3;
    const int h0 = (nt & 7) << 2;    // 4 output rows

    const u16* xsb = xs + (size_t)b * (32 * 32 * 512);

    // ---- A staging: 3072 chunks; ch = tid + k*512, k<6 (identical R11) ----
    const u16* asrc[6];
#pragma unroll
    for (int k = 0; k < 6; ++k) {
        int ch = tid + k * 512;
        int pp = ch >> 10, kc = (ch >> 8) & 3, co = ch & 255;
        asrc[k] = wbfT + ((size_t)(pp * 64 + kc) * 512 + mt * 256 + co) * 8;
    }
    auto stageA = [&](int buf) {
        char* d = (char*)ldsA[buf] + wv * 1024;
#pragma unroll
        for (int k = 0; k < 6; ++k) GLD16(asrc[k], d + k * 8192);
    };
    auto advA = [&](int dkf) {
#pragma unroll
        for (int k = 0; k < 6; ++k) asrc[k] += (long)dkf * 4096;
    };

    // ---- B staging: 816 chunks; ch = tid + k*512, k<2 (identical R11) ----
    const u16* bsrc[2]; bool binb[2];
#pragma unroll
    for (int k = 0; k < 2; ++k) {
        int ch = tid + k * 512;
        int kc = ch / 204, p = ch % 204;
        int rr = p / 34, cc = p % 34;
        int hh = h0 - 1 + rr, ww = cc - 1;
        binb[k] = (ch < 816) && ((unsigned)hh < 32u) && ((unsigned)ww < 32u);
        bsrc[k] = xsb + (hh * 32 + ww) * 512 + kc * 8;
    }
    auto stageB = [&](int buf) {
        char* d = (char*)ldsB[buf] + wv * 1024;
        GLD16(binb[0] ? bsrc[0] : zp, d);
        GLD16(binb[1] ? bsrc[1] : zp, d + 8192);
    };

    f32x16 acc[4][2] = {};           // [mf][nf], partial over ks' kc pair
    const int kcw = ks * 2 + kc8;    // this wave's kc for all frags

    // ---- prologue: A(t=0)->buf0, B(r0)->buf0 (identical R11) ----
    stageA(0);
    advA(192);
    stageB(0);
    asm volatile("s_waitcnt vmcnt(0)" ::: "memory");
    __builtin_amdgcn_s_barrier();

    int pidx = 0;
    for (int r = 0; r < 16; ++r) {
        const char* Bb = (const char*)ldsB[r & 1];
        const bool lastR = (r == 15);

#pragma unroll
        for (int phi = 0; phi < 3; ++phi) {
            const int abuf = pidx & 1;
            const char* Ab = (const char*)ldsA[abuf];
            const bool lastPhase = lastR && (phi == 2);

            // ---- 18 ds_read frags (12 A + 6 B), consecutive-16B ----
            bf16x8 af[3][4], bfr[3][2];
#pragma unroll
            for (int pp = 0; pp < 3; ++pp) {
#pragma unroll
                for (int mf = 0; mf < 4; ++mf) {
                    int co = wm * 128 + mf * 32 + l31;
                    af[pp][mf] = *reinterpret_cast<const bf16x8*>(
                        Ab + (((pp * 4 + kcw) * 256 + co) << 4));
                }
#pragma unroll
                for (int nf = 0; nf < 2; ++nf) {
                    int p = (wn * 2 + nf + phi) * 34 + l31 + pp;
                    bfr[pp][nf] = *reinterpret_cast<const bf16x8*>(
                        Bb + ((kcw * 204 + p) << 4));
                }
            }

            // ---- stage issues (identical R11) ----
            if (!lastPhase) {
                stageA(abuf ^ 1);
                advA(phi == 1 ? -380 : 192);
            }
            if (phi == 1 && !lastR) {
#pragma unroll
                for (int k = 0; k < 2; ++k) bsrc[k] += 32;
                stageB((r + 1) & 1);
            }

            __builtin_amdgcn_s_barrier();
            asm volatile("s_waitcnt lgkmcnt(0)" ::: "memory");
            __builtin_amdgcn_sched_barrier(0);

            __builtin_amdgcn_s_setprio(1);
#pragma unroll
            for (int pp = 0; pp < 3; ++pp)
#pragma unroll
                for (int mf = 0; mf < 4; ++mf) {
                    acc[mf][0] = __builtin_amdgcn_mfma_f32_32x32x16_bf16(
                        af[pp][mf], bfr[pp][0], acc[mf][0], 0, 0, 0);
                    acc[mf][1] = __builtin_amdgcn_mfma_f32_32x32x16_bf16(
                        af[pp][mf], bfr[pp][1], acc[mf][1], 0, 0, 0);
                }
            __builtin_amdgcn_s_setprio(0);
            __builtin_amdgcn_sched_barrier(0);

            if (!lastPhase) {
                asm volatile("s_waitcnt vmcnt(0)" ::: "memory");
                __builtin_amdgcn_s_barrier();
            }
            ++pidx;
        }
    }

    // ---- ks reduction through (now dead) ldsA/ldsB: pair = wm*2+wn ----
    const int pair = wm * 2 + wn;
    char* rb = (pair < 3) ? ((char*)ldsA + pair * 32768) : (char*)ldsB;

    __syncthreads();                 // all frag reads done; LDS reusable
    if (ks == 1) {
#pragma unroll
        for (int mf = 0; mf < 4; ++mf)
#pragma unroll
            for (int nf = 0; nf < 2; ++nf)
#pragma unroll
                for (int q4 = 0; q4 < 4; ++q4) {
                    float4 v = { acc[mf][nf][q4 * 4 + 0],
                                 acc[mf][nf][q4 * 4 + 1],
                                 acc[mf][nf][q4 * 4 + 2],
                                 acc[mf][nf][q4 * 4 + 3] };
                    *reinterpret_cast<float4*>(
                        rb + (((mf * 2 + nf) * 4 + q4) << 10) + lane * 16) = v;
                }
    }
    __syncthreads();

    if (ks == 0) {
        const float* db = dsc + b * 512;
#pragma unroll
        for (int mf = 0; mf < 4; ++mf) {
#pragma unroll
            for (int nf = 0; nf < 2; ++nf) {
#pragma unroll
                for (int q4 = 0; q4 < 4; ++q4) {
                    float4 v = *reinterpret_cast<const float4*>(
                        rb + (((mf * 2 + nf) * 4 + q4) << 10) + lane * 16);
                    acc[mf][nf][q4 * 4 + 0] += v.x;
                    acc[mf][nf][q4 * 4 + 1] += v.y;
                    acc[mf][nf][q4 * 4 + 2] += v.z;
                    acc[mf][nf][q4 * 4 + 3] += v.w;
                }
                const int h = h0 + wn * 2 + nf, w = l31;
#pragma unroll
                for (int q = 0; q < 16; ++q) {
                    int row = (q & 3) + 8 * (q >> 2) + 4 * kc8;
                    int co  = mt * 256 + wm * 128 + mf * 32 + row;
                    out[(((size_t)b * 512 + co) * 32 + h) * 32 + w]
                        = acc[mf][nf][q] * db[co];
                }
            }
        }
    }
}

// ---------------------------------------------------------------------------
extern "C" void kernel_launch(void* const* d_in, const int* in_sizes, int n_in,
                              void* d_out, int out_size, void* d_ws, size_t ws_size,
                              hipStream_t stream) {
    const float* x      = (const float*)d_in[0];
    const float* w      = (const float*)d_in[1];
    const float* mod_w  = (const float*)d_in[2];
    const float* mod_b  = (const float*)d_in[3];
    const float* ln_g   = (const float*)d_in[4];
    const float* ln_b   = (const float*)d_in[5];
    const float* weight = (const float*)d_in[6];
    const float* scale  = (const float*)d_in[7];
    float* out = (float*)d_out;

    char* ws = (char*)d_ws;
    float* s_raw = (float*)(ws);                     // 32 KB, reused as dsc
    float* dsc   = (float*)(ws);
    float* s_eff = (float*)(ws + 32768);             // 32 KB; head reused as zeros page
    float* wsq   = (float*)(ws + 65536);             // 1 MB
    u16*   wbfT  = (u16*)(ws + 65536 + 1048576);     // 4.5 MB
    u16*   xs    = (u16*)(ws + 65536 + 1048576 + 4718592);  // 16.78 MB
    if (ws_size < 22609920u) return;

    lin_kernel <<<2048, 256, 0, stream>>>(w, mod_w, mod_b, s_raw);
    wsq_kernel <<<1024, 256, 0, stream>>>(weight, wsq, wbfT);
    norm_kernel<<<16, 512, 0, stream>>>(s_raw, ln_g, ln_b, scale, s_eff);
    xs_kernel  <<<512, 256, 0, stream>>>(x, s_eff, xs);
    dsc_kernel <<<2048, 256, 0, stream>>>(s_eff, wsq, dsc);
    zfill_kernel<<<1, 1024, 0, stream>>>(s_eff);     // zeros page (s_eff dead now)
    conv_kernel<<<256, 512, 0, stream>>>(wbfT, xs, dsc, (const u16*)s_eff, out);
}

// Round 20
// 113.479 us; speedup vs baseline: 1.7211x; 1.0535x over previous
//
#include <hip/hip_runtime.h>

typedef unsigned short u16;
typedef __bf16 bf16x8 __attribute__((ext_vector_type(8)));
typedef float  f32x16 __attribute__((ext_vector_type(16)));

__device__ __forceinline__ u16 f2bf(float f) {
    union { float f; unsigned u; } v; v.f = f;
    return (u16)((v.u + 0x7fffu + ((v.u >> 16) & 1u)) >> 16);
}

#define GLD16(gsrc, ldst) \
    __builtin_amdgcn_global_load_lds( \
        (const __attribute__((address_space(1))) void*)(gsrc), \
        (__attribute__((address_space(3))) void*)(ldst), 16, 0, 0)

// ---------------------------------------------------------------------------
// 1) s_raw[b][c] = w[b] @ mod_w[c] + mod_b[c]
// ---------------------------------------------------------------------------
__global__ __launch_bounds__(256) void lin_kernel(
    const float* __restrict__ w, const float* __restrict__ mod_w,
    const float* __restrict__ mod_b, float* __restrict__ s_raw)
{
    int gw = (blockIdx.x * 256 + threadIdx.x) >> 6;
    int lane = threadIdx.x & 63;
    int b = gw >> 9, c = gw & 511;
    const float* wr = w + b * 512;
    const float* mr = mod_w + (size_t)c * 512;
    float a = 0.f;
#pragma unroll
    for (int i = 0; i < 8; ++i)
        a = fmaf(wr[lane + i * 64], mr[lane + i * 64], a);
    for (int off = 32; off; off >>= 1) a += __shfl_down(a, off);
    if (!lane) s_raw[gw] = a + mod_b[c];
}

// ---------------------------------------------------------------------------
// 2) s_eff = LeakyReLU(LN(s_raw)) * scale
// ---------------------------------------------------------------------------
__global__ __launch_bounds__(512) void norm_kernel(
    const float* __restrict__ s_raw, const float* __restrict__ ln_g,
    const float* __restrict__ ln_b, const float* __restrict__ scale,
    float* __restrict__ s_eff)
{
    int b = blockIdx.x, c = threadIdx.x;
    __shared__ float rs[512], rq[512];
    float s = s_raw[b * 512 + c];
    rs[c] = s; rq[c] = s * s;
    __syncthreads();
    for (int off = 256; off; off >>= 1) {
        if (c < off) { rs[c] += rs[c + off]; rq[c] += rq[c + off]; }
        __syncthreads();
    }
    float mean = rs[0] * (1.f / 512.f);
    float var  = rq[0] * (1.f / 512.f) - mean * mean;
    float sn = (s - mean) * rsqrtf(var + 1e-5f) * ln_g[c] + ln_b[c];
    sn = sn >= 0.f ? sn : 0.2f * sn;
    s_eff[b * 512 + c] = sn * scale[c];
}

// ---------------------------------------------------------------------------
// 3) wsq[co][ci] = sum_p weight^2 ; wbfT[(p*64+cg)*512*8 + co*8 + cj] = bf16(w)
// ---------------------------------------------------------------------------
__global__ __launch_bounds__(256) void wsq_kernel(
    const float* __restrict__ weight, float* __restrict__ wsq, u16* __restrict__ wbfT)
{
    int idx = blockIdx.x * 256 + threadIdx.x;      // co*512+ci
    int co = idx >> 9, ci = idx & 511;
    int cg = ci >> 3, cj = ci & 7;
    const float* wp = weight + (size_t)idx * 9;
    float s = 0.f;
#pragma unroll
    for (int p = 0; p < 9; ++p) {
        float v = wp[p];
        s += v * v;
        wbfT[((size_t)(p * 64 + cg) * 512 + co) * 8 + cj] = f2bf(v);
    }
    wsq[idx] = s;
}

// ---------------------------------------------------------------------------
// 4) xs[b][h][w][c] (NHWC bf16) = bf16(x[b][c][h][w] * s_eff[b][c])
// ---------------------------------------------------------------------------
__global__ __launch_bounds__(256) void xs_kernel(
    const float* __restrict__ x, const float* __restrict__ s_eff,
    u16* __restrict__ xs)
{
    const int bh = blockIdx.x;
    const int b = bh >> 5, h = bh & 31;
    __shared__ float tile[64][33];
    for (int c0 = 0; c0 < 512; c0 += 64) {
        if (c0) __syncthreads();
        for (int idx = threadIdx.x; idx < 2048; idx += 256) {
            int c = idx >> 5, ww = idx & 31;
            tile[c][ww] = x[(((size_t)b * 512 + c0 + c) * 32 + h) * 32 + ww]
                          * s_eff[b * 512 + c0 + c];
        }
        __syncthreads();
        for (int idx = threadIdx.x; idx < 2048; idx += 256) {
            int ww = idx >> 6, c = idx & 63;
            xs[((b * 32 + h) * 32 + ww) * 512 + c0 + c] = f2bf(tile[c][ww]);
        }
    }
}

// ---------------------------------------------------------------------------
// 5) dsc[b][o] = rsqrt(sum_i s_eff[b][i]^2 * wsq[o][i] + 1e-8)
// ---------------------------------------------------------------------------
__global__ __launch_bounds__(256) void dsc_kernel(
    const float* __restrict__ s_eff, const float* __restrict__ wsq,
    float* __restrict__ dsc)
{
    int gw = (blockIdx.x * 256 + threadIdx.x) >> 6;
    int lane = threadIdx.x & 63;
    int b = gw >> 9, co = gw & 511;
    float a = 0.f;
#pragma unroll
    for (int i = 0; i < 8; ++i) {
        int cin = lane + i * 64;
        float se = s_eff[b * 512 + cin];
        a += se * se * wsq[co * 512 + cin];
    }
    for (int off = 32; off; off >>= 1) a += __shfl_down(a, off);
    if (!lane) dsc[gw] = rsqrtf(a + 1e-8f);
}

// ---------------------------------------------------------------------------
// 6) zero page for halo OOB lanes
// ---------------------------------------------------------------------------
__global__ void zfill_kernel(float* p) { p[threadIdx.x] = 0.f; }

// ---------------------------------------------------------------------------
// 7) conv, R11 phase machine with SGB-PINNED pp-pipeline (T19).
//    Compute section per phase: R(0) R(1) M(0) R(2) M(1) M(2), chunks of
//    8 ds_read / 8 MFMA pinned via sched_group_barrier -> each MFMA chunk
//    consumes reads issued ONE chunk earlier; compiler inserts counted
//    lgkmcnt. LDS pipe (2304 cyc/CU-phase) overlaps MFMA pipe (1536/SIMD)
//    instead of running sequentially (R11's measured 4390 = 2304+1536+550).
//    ONE barrier per phase (mid-phase barrier proven redundant: reads
//    complete before each wave's own MFMAs; stages target opposite bufs).
//    Geometry/layout/staging byte-identical to R11 (87.8us): grid 256 =
//    2 mt x 128 strips, 8 waves (4wm x 2wn), 64x64 wave tile, kc-major
//    conflict-free LDS, A 2x48KB phase-dbuf, B 2x16KB round-dbuf.
// ---------------------------------------------------------------------------
__global__ __launch_bounds__(512, 1) void conv_kernel(
    const u16* __restrict__ wbfT,  // [576 kflat8][512 co][8]
    const u16* __restrict__ xs,    // [16][32][32][512]
    const float* __restrict__ dsc, // [16][512]
    const u16* __restrict__ zp,    // >=16B zeros
    float* __restrict__ out)       // [16][512][32][32]
{
    __shared__ __align__(16) u16 ldsA[2][24576];   // 2 x 48 KB
    __shared__ __align__(16) u16 ldsB[2][8192];    // 2 x 16 KB (13056 used)

    const int tid  = threadIdx.x;
    const int lane = tid & 63;
    const int wv   = tid >> 6;       // 0..7
    const int wm   = wv >> 1;        // 0..3  M-wave (64 co each)
    const int wn   = wv & 1;         // 0..1  N-wave (64 px each)
    const int l31  = lane & 31;
    const int kc8  = lane >> 5;

    const int bx = blockIdx.x;       // 256 blocks
    const int mt = bx & 1;           // XCD-parity-pinned cout half
    const int nt = bx >> 1;          // 0..127
    const int b  = nt >> 3;
    const int h0 = (nt & 7) << 2;    // 4 output rows

    const u16* xsb = xs + (size_t)b * (32 * 32 * 512);

    // ---- A staging: 3072 chunks; ch = tid + k*512, k<6 (identical R11) ----
    const u16* asrc[6];
#pragma unroll
    for (int k = 0; k < 6; ++k) {
        int ch = tid + k * 512;
        int pp = ch >> 10, kc = (ch >> 8) & 3, co = ch & 255;
        asrc[k] = wbfT + ((size_t)(pp * 64 + kc) * 512 + mt * 256 + co) * 8;
    }
    auto stageA = [&](int buf) {
        char* d = (char*)ldsA[buf] + wv * 1024;
#pragma unroll
        for (int k = 0; k < 6; ++k) GLD16(asrc[k], d + k * 8192);
    };
    auto advA = [&](int dkf) {
#pragma unroll
        for (int k = 0; k < 6; ++k) asrc[k] += (long)dkf * 4096;
    };

    // ---- B staging: 816 chunks; ch = tid + k*512, k<2 (identical R11) ----
    const u16* bsrc[2]; bool binb[2];
#pragma unroll
    for (int k = 0; k < 2; ++k) {
        int ch = tid + k * 512;
        int kc = ch / 204, p = ch % 204;
        int rr = p / 34, cc = p % 34;
        int hh = h0 - 1 + rr, ww = cc - 1;
        binb[k] = (ch < 816) && ((unsigned)hh < 32u) && ((unsigned)ww < 32u);
        bsrc[k] = xsb + (hh * 32 + ww) * 512 + kc * 8;
    }
    auto stageB = [&](int buf) {
        char* d = (char*)ldsB[buf] + wv * 1024;
        GLD16(binb[0] ? bsrc[0] : zp, d);
        GLD16(binb[1] ? bsrc[1] : zp, d + 8192);
    };

    f32x16 acc[2][2] = {};

    // ---- prologue: A(t=0)->buf0, B(r0)->buf0; full drain ----
    stageA(0);
    advA(192);
    stageB(0);
    asm volatile("s_waitcnt vmcnt(0)" ::: "memory");
    __builtin_amdgcn_s_barrier();

    // read chunk pp: 4 A-frags + 4 B-frags (8 ds_read_b128)
#define RD(PP) do {                                                         \
    _Pragma("unroll")                                                       \
    for (int kk = 0; kk < 2; ++kk) {                                        \
        const int kc_ = kk * 2 + kc8;                                       \
        _Pragma("unroll")                                                   \
        for (int mf = 0; mf < 2; ++mf) {                                    \
            int co_ = wm * 64 + mf * 32 + l31;                              \
            af[PP][mf][kk] = *reinterpret_cast<const bf16x8*>(              \
                Ab + ((((PP) * 4 + kc_) * 256 + co_) << 4));                \
        }                                                                   \
        _Pragma("unroll")                                                   \
        for (int nf = 0; nf < 2; ++nf) {                                    \
            int p_ = (wn * 2 + nf + phi) * 34 + l31 + (PP);                 \
            bfr[PP][nf][kk] = *reinterpret_cast<const bf16x8*>(             \
                Bb + ((kc_ * 204 + p_) << 4));                              \
        }                                                                   \
    }                                                                       \
} while (0)

#define MM(PP) do {                                                         \
    _Pragma("unroll")                                                       \
    for (int kk = 0; kk < 2; ++kk) {                                        \
        acc[0][0] = __builtin_amdgcn_mfma_f32_32x32x16_bf16(                \
            af[PP][0][kk], bfr[PP][0][kk], acc[0][0], 0, 0, 0);             \
        acc[0][1] = __builtin_amdgcn_mfma_f32_32x32x16_bf16(                \
            af[PP][0][kk], bfr[PP][1][kk], acc[0][1], 0, 0, 0);             \
        acc[1][0] = __builtin_amdgcn_mfma_f32_32x32x16_bf16(                \
            af[PP][1][kk], bfr[PP][0][kk], acc[1][0], 0, 0, 0);             \
        acc[1][1] = __builtin_amdgcn_mfma_f32_32x32x16_bf16(                \
            af[PP][1][kk], bfr[PP][1][kk], acc[1][1], 0, 0, 0);             \
    }                                                                       \
} while (0)

#define SGB_DS  __builtin_amdgcn_sched_group_barrier(0x100, 8, 0)
#define SGB_MF  __builtin_amdgcn_sched_group_barrier(0x8, 8, 0)

    int pidx = 0;
    for (int r = 0; r < 16; ++r) {
        const char* Bb = (const char*)ldsB[r & 1];
        const bool lastR = (r == 15);

#pragma unroll
        for (int phi = 0; phi < 3; ++phi) {
            const int abuf = pidx & 1;
            const char* Ab = (const char*)ldsA[abuf];
            const bool lastPhase = lastR && (phi == 2);

            // ---- stage issues first (whole phase to land) ----
            if (!lastPhase) {
                stageA(abuf ^ 1);
                advA(phi == 1 ? -380 : 192);
            }
            if (phi == 1 && !lastR) {
#pragma unroll
                for (int k = 0; k < 2; ++k) bsrc[k] += 32;
                stageB((r + 1) & 1);
            }

            // ---- SGB-pinned pp-pipeline: R0 R1 M0 R2 M1 M2 ----
            bf16x8 af[3][2][2], bfr[3][2][2];
            RD(0); SGB_DS;
            RD(1); SGB_DS;
            MM(0); SGB_MF;
            RD(2); SGB_DS;
            MM(1); SGB_MF;
            MM(2); SGB_MF;

            // ---- phase tail: staged loads drained; single barrier ----
            if (!lastPhase) {
                asm volatile("s_waitcnt vmcnt(0)" ::: "memory");
                __builtin_amdgcn_s_barrier();
            }
            ++pidx;
        }
    }
#undef RD
#undef MM
#undef SGB_DS
#undef SGB_MF

    // ---- epilogue: C/D col=lane&31, row=(q&3)+8*(q>>2)+4*(lane>>5) ----
    const float* db = dsc + b * 512;
#pragma unroll
    for (int mf = 0; mf < 2; ++mf) {
#pragma unroll
        for (int nf = 0; nf < 2; ++nf) {
            const int h = h0 + wn * 2 + nf, w = l31;
#pragma unroll
            for (int q = 0; q < 16; ++q) {
                int row = (q & 3) + 8 * (q >> 2) + 4 * kc8;
                int co  = mt * 256 + wm * 64 + mf * 32 + row;
                out[(((size_t)b * 512 + co) * 32 + h) * 32 + w]
                    = acc[mf][nf][q] * db[co];
            }
        }
    }
}

// ---------------------------------------------------------------------------
extern "C" void kernel_launch(void* const* d_in, const int* in_sizes, int n_in,
                              void* d_out, int out_size, void* d_ws, size_t ws_size,
                              hipStream_t stream) {
    const float* x      = (const float*)d_in[0];
    const float* w      = (const float*)d_in[1];
    const float* mod_w  = (const float*)d_in[2];
    const float* mod_b  = (const float*)d_in[3];
    const float* ln_g   = (const float*)d_in[4];
    const float* ln_b   = (const float*)d_in[5];
    const float* weight = (const float*)d_in[6];
    const float* scale  = (const float*)d_in[7];
    float* out = (float*)d_out;

    char* ws = (char*)d_ws;
    float* s_raw = (float*)(ws);                     // 32 KB, reused as dsc
    float* dsc   = (float*)(ws);
    float* s_eff = (float*)(ws + 32768);             // 32 KB; head reused as zeros page
    float* wsq   = (float*)(ws + 65536);             // 1 MB
    u16*   wbfT  = (u16*)(ws + 65536 + 1048576);     // 4.5 MB
    u16*   xs    = (u16*)(ws + 65536 + 1048576 + 4718592);  // 16.78 MB
    if (ws_size < 22609920u) return;

    lin_kernel <<<2048, 256, 0, stream>>>(w, mod_w, mod_b, s_raw);
    wsq_kernel <<<1024, 256, 0, stream>>>(weight, wsq, wbfT);
    norm_kernel<<<16, 512, 0, stream>>>(s_raw, ln_g, ln_b, scale, s_eff);
    xs_kernel  <<<512, 256, 0, stream>>>(x, s_eff, xs);
    dsc_kernel <<<2048, 256, 0, stream>>>(s_eff, wsq, dsc);
    zfill_kernel<<<1, 1024, 0, stream>>>(s_eff);     // zeros page (s_eff dead now)
    conv_kernel<<<256, 512, 0, stream>>>(wbfT, xs, dsc, (const u16*)s_eff, out);
}